// Round 1
// baseline (28486.279 us; speedup 1.0000x reference)
//
#include <hip/hip_runtime.h>

#define B_ 16
#define V_ 2
#define G_ 7
#define PATCH_ 14
#define SG_ 16
#define D_ 768
#define NH_ 12
#define L_ 12
#define DH_ 64
#define N_ 49
#define S_ 256

__device__ __forceinline__ unsigned short f2bf(float f) {
  unsigned int u = __builtin_bit_cast(unsigned int, f);
  u += 0x7fffu + ((u >> 16) & 1u);
  return (unsigned short)(u >> 16);
}
__device__ __forceinline__ float bf2f(unsigned short h) {
  unsigned int u = ((unsigned int)h) << 16;
  return __builtin_bit_cast(float, u);
}

using bf16x8 = __attribute__((ext_vector_type(8))) __bf16;
using u16x8  = __attribute__((ext_vector_type(8))) unsigned short;
using f32x4  = __attribute__((ext_vector_type(4))) float;

// ---------------------------------------------------------------- GEMM ----
// C(MxN) = A(MxK bf16, row-major lda) @ W(N x ldw fp32, row-major)^T + bias
// epi: 0 = none, 1 = gelu(tanh approx), 2 = res + gate*val
// Writes Cf (fp32) and/or Cb (bf16), both ldc.
__global__ __launch_bounds__(256) void gemm_bias(
    const unsigned short* __restrict__ A, int lda,
    const float* __restrict__ W, int ldw,
    const float* __restrict__ bias,
    float* __restrict__ Cf, unsigned short* __restrict__ Cb, int ldc,
    const float* __restrict__ res, const float* __restrict__ gate,
    int M, int N, int K, int epi)
{
  __shared__ unsigned short As[64][40];
  __shared__ unsigned short Bs[64][40];
  const int m0 = blockIdx.x * 64, n0 = blockIdx.y * 64;
  const int tid = threadIdx.x, lane = tid & 63, wid = tid >> 6;
  const int wr = wid >> 1, wc = wid & 1;
  f32x4 acc00 = {0.f,0.f,0.f,0.f}, acc01 = {0.f,0.f,0.f,0.f};
  f32x4 acc10 = {0.f,0.f,0.f,0.f}, acc11 = {0.f,0.f,0.f,0.f};
  const int srow = tid >> 2, scol = (tid & 3) * 8;
  const int kb = (lane >> 4) * 8;
  const int fr = lane & 15;

  for (int k0 = 0; k0 < K; k0 += 32) {
    __syncthreads();
    {
      int gr = m0 + srow;
      u16x8 va = {0,0,0,0,0,0,0,0};
      if (gr < M) va = *(const u16x8*)(A + (size_t)gr * lda + k0 + scol);
      *(u16x8*)&As[srow][scol] = va;
      int gn = n0 + srow;
      const float* wrp = W + (size_t)gn * ldw + k0 + scol;
      u16x8 vb;
#pragma unroll
      for (int i = 0; i < 8; ++i) {
        int kk = k0 + scol + i;
        vb[i] = f2bf(kk < ldw ? wrp[i] : 0.0f);
      }
      *(u16x8*)&Bs[srow][scol] = vb;
    }
    __syncthreads();
    bf16x8 a0 = __builtin_bit_cast(bf16x8, *(const u16x8*)&As[wr*32 + fr][kb]);
    bf16x8 a1 = __builtin_bit_cast(bf16x8, *(const u16x8*)&As[wr*32 + 16 + fr][kb]);
    bf16x8 b0 = __builtin_bit_cast(bf16x8, *(const u16x8*)&Bs[wc*32 + fr][kb]);
    bf16x8 b1 = __builtin_bit_cast(bf16x8, *(const u16x8*)&Bs[wc*32 + 16 + fr][kb]);
    acc00 = __builtin_amdgcn_mfma_f32_16x16x32_bf16(a0, b0, acc00, 0, 0, 0);
    acc01 = __builtin_amdgcn_mfma_f32_16x16x32_bf16(a0, b1, acc01, 0, 0, 0);
    acc10 = __builtin_amdgcn_mfma_f32_16x16x32_bf16(a1, b0, acc10, 0, 0, 0);
    acc11 = __builtin_amdgcn_mfma_f32_16x16x32_bf16(a1, b1, acc11, 0, 0, 0);
  }

  const int er = (lane >> 4) * 4;
  const int ec = lane & 15;
#define EPILOGUE(ACC, FI, FJ) do { \
    int gc = n0 + wc*32 + (FJ)*16 + ec; \
    float bi = bias ? bias[gc] : 0.0f; \
    float gg = gate ? gate[gc] : 1.0f; \
    _Pragma("unroll") \
    for (int i = 0; i < 4; ++i) { \
      int gr = m0 + wr*32 + (FI)*16 + er + i; \
      if (gr < M) { \
        float v = ACC[i] + bi; \
        if (epi == 1) { float xx = v; v = 0.5f*xx*(1.0f + tanhf(0.79788456080286536f*(xx + 0.044715f*xx*xx*xx))); } \
        else if (epi == 2) { v = res[(size_t)gr*ldc + gc] + gg*v; } \
        if (Cf) Cf[(size_t)gr*ldc + gc] = v; \
        if (Cb) Cb[(size_t)gr*ldc + gc] = f2bf(v); \
      } \
    } \
  } while (0)
  EPILOGUE(acc00, 0, 0);
  EPILOGUE(acc01, 0, 1);
  EPILOGUE(acc10, 1, 0);
  EPILOGUE(acc11, 1, 1);
#undef EPILOGUE
}

// ----------------------------------------------------------- attention ----
// One block per (b, head). K/V staged (bf16, XOR-swizzled) with RoPE on K.
// Each wave handles query rows r = wid, wid+4, ...
#define KSW(t, d) (((t) << 6) + ((d) ^ (((t) & 31) << 1)))

__global__ __launch_bounds__(256) void attn_kernel(
    const float* __restrict__ Q, int ldq, int qoff, int Lq,
    const float* __restrict__ KV, int ldkv, int koff, int voff, int Lk,
    const float* __restrict__ cq, const float* __restrict__ sq, int rbq,
    const float* __restrict__ ck, const float* __restrict__ sk, int rbk,
    unsigned short* __restrict__ Out)
{
  __shared__ unsigned short Kl[S_ * DH_];
  __shared__ unsigned short Vl[S_ * DH_];
  __shared__ float qrow[4][DH_];
  __shared__ float pbuf[4][S_];
  const int b = blockIdx.x / NH_, h = blockIdx.x - b * NH_;
  const int tid = threadIdx.x, lane = tid & 63, wid = tid >> 6;

  for (int idx = tid; idx < Lk * 32; idx += 256) {
    int t = idx >> 5, m = idx & 31;
    size_t rowb = ((size_t)b * Lk + t) * ldkv;
    const float* kr = KV + rowb + koff + h * DH_;
    const float* vr = KV + rowb + voff + h * DH_;
    float k1 = kr[2*m], k2 = kr[2*m+1];
    size_t ri = (size_t)b * rbk + t * 32 + m;
    float c = ck[ri], s = sk[ri];
    unsigned int kw = (unsigned int)f2bf(k1*c - k2*s) | ((unsigned int)f2bf(k1*s + k2*c) << 16);
    unsigned int vw = (unsigned int)f2bf(vr[2*m]) | ((unsigned int)f2bf(vr[2*m+1]) << 16);
    ((unsigned int*)Kl)[KSW(t, 2*m) >> 1] = kw;
    ((unsigned int*)Vl)[KSW(t, 2*m) >> 1] = vw;
  }
  __syncthreads();

  const int nt = (Lk + 63) >> 6;
  for (int r = wid; r < Lq; r += 4) {
    float x = Q[((size_t)b * Lq + r) * ldq + qoff + h * DH_ + lane];
    float px = __shfl_xor(x, 1);
    int m = lane >> 1;
    size_t ri = (size_t)b * rbq + r * 32 + m;
    float c = cq[ri], s = sq[ri];
    float qr = (lane & 1) ? (px * s + x * c) : (x * c - px * s);
    qrow[wid][lane] = qr;
    __asm__ volatile("s_waitcnt lgkmcnt(0)" ::: "memory");

    float sc0 = -1e30f, sc1 = -1e30f, sc2 = -1e30f, sc3 = -1e30f;
    for (int j = 0; j < nt; ++j) {
      int t = lane + (j << 6);
      float acc = -1e30f;
      if (t < Lk) {
        int sw = (t & 31) << 1;
        const unsigned short* kp = Kl + (t << 6);
        float a0 = 0.f, a1 = 0.f, a2 = 0.f, a3 = 0.f;
#pragma unroll 4
        for (int d = 0; d < 64; d += 4) {
          a0 += qrow[wid][d]   * bf2f(kp[(d)   ^ sw]);
          a1 += qrow[wid][d+1] * bf2f(kp[(d+1) ^ sw]);
          a2 += qrow[wid][d+2] * bf2f(kp[(d+2) ^ sw]);
          a3 += qrow[wid][d+3] * bf2f(kp[(d+3) ^ sw]);
        }
        acc = ((a0 + a1) + (a2 + a3)) * 0.125f;
      }
      if (j == 0) sc0 = acc; else if (j == 1) sc1 = acc; else if (j == 2) sc2 = acc; else sc3 = acc;
    }
    float mx = fmaxf(fmaxf(sc0, sc1), fmaxf(sc2, sc3));
    for (int o = 32; o; o >>= 1) mx = fmaxf(mx, __shfl_xor(mx, o));
    float sum;
    { float e = expf(sc0 - mx); pbuf[wid][lane] = e; sum = e; }
    if (nt > 1) { float e = expf(sc1 - mx); pbuf[wid][lane + 64]  = e; sum += e; }
    if (nt > 2) { float e = expf(sc2 - mx); pbuf[wid][lane + 128] = e; sum += e; }
    if (nt > 3) { float e = expf(sc3 - mx); pbuf[wid][lane + 192] = e; sum += e; }
    for (int o = 32; o; o >>= 1) sum += __shfl_xor(sum, o);
    float inv = 1.0f / sum;

    float o0 = 0.f, o1 = 0.f, o2 = 0.f, o3 = 0.f;
    int t = 0;
    for (; t + 3 < Lk; t += 4) {
      o0 += pbuf[wid][t]   * bf2f(Vl[KSW(t,   lane)]);
      o1 += pbuf[wid][t+1] * bf2f(Vl[KSW(t+1, lane)]);
      o2 += pbuf[wid][t+2] * bf2f(Vl[KSW(t+2, lane)]);
      o3 += pbuf[wid][t+3] * bf2f(Vl[KSW(t+3, lane)]);
    }
    for (; t < Lk; ++t) o0 += pbuf[wid][t] * bf2f(Vl[KSW(t, lane)]);
    float od = (o0 + o1) + (o2 + o3);
    Out[((size_t)b * Lq + r) * D_ + h * DH_ + lane] = f2bf(od * inv);
  }
}

// ----------------------------------------------------------- layernorm ----
__global__ __launch_bounds__(256) void ln_kernel(
    const float* __restrict__ X, const float* __restrict__ w,
    const float* __restrict__ bsh, unsigned short* __restrict__ Out)
{
  const int row = blockIdx.x, tid = threadIdx.x;
  const float* x = X + (size_t)row * D_;
  float v0 = x[tid], v1 = x[tid + 256], v2 = x[tid + 512];
  __shared__ float red[4];
  float s = v0 + v1 + v2;
  for (int o = 32; o; o >>= 1) s += __shfl_xor(s, o);
  if ((tid & 63) == 0) red[tid >> 6] = s;
  __syncthreads();
  float mean = (red[0] + red[1] + red[2] + red[3]) * (1.0f / 768.0f);
  float d0 = v0 - mean, d1 = v1 - mean, d2 = v2 - mean;
  float q = d0*d0 + d1*d1 + d2*d2;
  __syncthreads();
  for (int o = 32; o; o >>= 1) q += __shfl_xor(q, o);
  if ((tid & 63) == 0) red[tid >> 6] = q;
  __syncthreads();
  float var = (red[0] + red[1] + red[2] + red[3]) * (1.0f / 768.0f);
  float rstd = rsqrtf(var + 1e-6f);
  Out[(size_t)row*D_ + tid]       = f2bf(d0 * rstd * w[tid]       + bsh[tid]);
  Out[(size_t)row*D_ + tid + 256] = f2bf(d1 * rstd * w[tid + 256] + bsh[tid + 256]);
  Out[(size_t)row*D_ + tid + 512] = f2bf(d2 * rstd * w[tid + 512] + bsh[tid + 512]);
}

// --------------------------------------------------------------- misc ----
__global__ void init_scene_k(const float* __restrict__ tok, float* __restrict__ sf,
                             unsigned short* __restrict__ sb, int total) {
  int i = blockIdx.x * 256 + threadIdx.x;
  if (i < total) {
    float v = tok[i % (S_ * D_)];
    sf[i] = v; sb[i] = f2bf(v);
  }
}

__global__ void rope_scene_k(float* __restrict__ c, float* __restrict__ s) {
  int idx = blockIdx.x * 256 + threadIdx.x;
  if (idx >= S_ * 32) return;
  int t = idx >> 5, m = idx & 31;
  int i = t >> 4, j = t & 15;
  float xx = -1.0f + 2.0f * j / 15.0f;
  float yy = -1.0f + 2.0f * i / 15.0f;
  float coord = (m < 16) ? xx : yy;
  float per = powf(100.0f, (float)(m & 15) / 16.0f);
  float ang = coord / per;
  c[idx] = cosf(ang); s[idx] = sinf(ang);
}

__global__ void rope_local_k(float* __restrict__ c, float* __restrict__ s,
                             const float* __restrict__ ctr, const float* __restrict__ scl) {
  int idx = blockIdx.x * 256 + threadIdx.x;
  if (idx >= B_ * N_ * 32) return;
  int b = idx / (N_ * 32);
  int r = idx - b * (N_ * 32);
  int pch = r >> 5, m = r & 31;
  int py = pch / 7, px = pch - py * 7;
  float cx = ctr[b*2], cy = ctr[b*2+1], sc = scl[b];
  float gx = cx + sc * ((px - 3.0f) / 3.0f);
  float gy = cy + sc * ((py - 3.0f) / 3.0f);
  float coord = (m < 16) ? gx : gy;
  float per = powf(100.0f, (float)(m & 15) / 16.0f);
  float ang = coord / per;
  c[idx] = cosf(ang); s[idx] = sinf(ang);
}

// bilinear glimpse sample -> im2col row (b*49+p), col c*196+i*14+j, K padded to 608
__global__ void im2col_k(unsigned short* __restrict__ xb, const float* __restrict__ img,
                         const float* __restrict__ ctr, const float* __restrict__ scl) {
  int idx = blockIdx.x * 256 + threadIdx.x;
  if (idx >= 784 * 608) return;
  int row = idx / 608, col = idx - row * 608;
  float val = 0.0f;
  if (col < 588) {
    int b = row / 49, pch = row - b * 49;
    int c = col / 196, rr = col - c * 196;
    int i = rr / 14, j = rr - i * 14;
    int py = pch / 7, px = pch - py * 7;
    int gyi = py * 14 + i, gxi = px * 14 + j;
    float cx = ctr[b*2], cy = ctr[b*2+1], sc = scl[b];
    float gy = cy + sc * (-1.0f + 2.0f * gyi / 97.0f);
    float gx = cx + sc * (-1.0f + 2.0f * gxi / 97.0f);
    float pyi = (gy + 1.0f) * 0.5f * 223.0f;
    float pxi = (gx + 1.0f) * 0.5f * 223.0f;
    float y0f = fminf(fmaxf(floorf(pyi), 0.0f), 222.0f);
    float x0f = fminf(fmaxf(floorf(pxi), 0.0f), 222.0f);
    int y0 = (int)y0f, x0 = (int)x0f;
    float wy = fminf(fmaxf(pyi - y0f, 0.0f), 1.0f);
    float wx = fminf(fmaxf(pxi - x0f, 0.0f), 1.0f);
    const float* base = img + (size_t)(b * 3 + c) * 224 * 224;
    float v00 = base[y0*224 + x0],       v01 = base[y0*224 + x0 + 1];
    float v10 = base[(y0+1)*224 + x0],   v11 = base[(y0+1)*224 + x0 + 1];
    val = (v00*(1.0f-wy) + v10*wy)*(1.0f-wx) + (v01*(1.0f-wy) + v11*wy)*wx;
  }
  xb[idx] = f2bf(val);
}

// -------------------------------------------------------------- launch ----
extern "C" void kernel_launch(void* const* d_in, const int* in_sizes, int n_in,
                              void* d_out, int out_size, void* d_ws, size_t ws_size,
                              hipStream_t stream) {
  const float* images    = (const float*)d_in[0];
  const float* centers   = (const float*)d_in[1];
  const float* scales    = (const float*)d_in[2];
  const float* patch_w   = (const float*)d_in[3];
  const float* patch_b   = (const float*)d_in[4];
  const float* scene_tok = (const float*)d_in[5];
  const float* ln1_w = (const float*)d_in[6];
  const float* ln1_b = (const float*)d_in[7];
  const float* ln2_w = (const float*)d_in[8];
  const float* ln2_b = (const float*)d_in[9];
  const float* qkv_w = (const float*)d_in[10];
  const float* qkv_b = (const float*)d_in[11];
  const float* ao_w  = (const float*)d_in[12];
  const float* ao_b  = (const float*)d_in[13];
  const float* m1_w  = (const float*)d_in[14];
  const float* m1_b  = (const float*)d_in[15];
  const float* m2_w  = (const float*)d_in[16];
  const float* m2_b  = (const float*)d_in[17];
  const float* rq_w  = (const float*)d_in[18];
  const float* rq_b  = (const float*)d_in[19];
  const float* rkv_w = (const float*)d_in[20];
  const float* rkv_b = (const float*)d_in[21];
  const float* ro_w  = (const float*)d_in[22];
  const float* ro_b  = (const float*)d_in[23];
  const float* rgate = (const float*)d_in[24];
  const float* wq_w  = (const float*)d_in[25];
  const float* wq_b  = (const float*)d_in[26];
  const float* wkv_w = (const float*)d_in[27];
  const float* wkv_b = (const float*)d_in[28];
  const float* wo_w  = (const float*)d_in[29];
  const float* wo_b  = (const float*)d_in[30];
  const float* wgate = (const float*)d_in[31];

  float* scene_f = (float*)d_out;

  char* p = (char*)d_ws;
  auto alloc = [&](size_t bytes) { char* r = p; p += (bytes + 255) & ~(size_t)255; return (void*)r; };
  unsigned short* scene_bf = (unsigned short*)alloc((size_t)B_*S_*D_*2);
  float*          local_f  = (float*)alloc((size_t)B_*N_*D_*4);
  unsigned short* local_bf = (unsigned short*)alloc((size_t)B_*N_*D_*2);
  float*          q_buf    = (float*)alloc((size_t)B_*S_*D_*4);
  float*          kv_buf   = (float*)alloc((size_t)B_*S_*1536*4);
  unsigned short* ln_bf    = (unsigned short*)alloc((size_t)B_*N_*D_*2);
  unsigned short* act_bf   = (unsigned short*)alloc((size_t)B_*S_*D_*2);
  unsigned short* x_bf     = (unsigned short*)alloc((size_t)B_*N_*608*2);
  float* sc_cos = (float*)alloc((size_t)S_*32*4);
  float* sc_sin = (float*)alloc((size_t)S_*32*4);
  float* l_cos  = (float*)alloc((size_t)B_*N_*32*4);
  float* l_sin  = (float*)alloc((size_t)B_*N_*32*4);

  auto gemm = [&](const unsigned short* A, int lda, const float* Wp, int ldw,
                  const float* bias, float* Cf, unsigned short* Cb, int ldc,
                  const float* res, const float* gt, int M, int N, int K, int epi) {
    dim3 g((M + 63) / 64, N / 64);
    gemm_bias<<<g, 256, 0, stream>>>(A, lda, Wp, ldw, bias, Cf, Cb, ldc, res, gt, M, N, K, epi);
  };

  {
    int total = B_ * S_ * D_;
    init_scene_k<<<(total + 255) / 256, 256, 0, stream>>>(scene_tok, scene_f, scene_bf, total);
    rope_scene_k<<<(S_*32 + 255) / 256, 256, 0, stream>>>(sc_cos, sc_sin);
  }

  for (int vp = 0; vp < V_; ++vp) {
    const float* ctr = centers + (size_t)vp * B_ * 2;
    const float* scl = scales + (size_t)vp * B_;
    rope_local_k<<<(B_*N_*32 + 255) / 256, 256, 0, stream>>>(l_cos, l_sin, ctr, scl);
    im2col_k<<<(784*608 + 255) / 256, 256, 0, stream>>>(x_bf, images, ctr, scl);
    // patch conv as GEMM (K padded 588->608)
    gemm(x_bf, 608, patch_w, 588, patch_b, local_f, local_bf, 768,
         nullptr, nullptr, 784, 768, 608, 0);

    for (int l = 0; l < L_; ++l) {
      // ---- read cross (local queries scene) ----
      gemm(local_bf, 768, rq_w + (size_t)l*768*768, 768, rq_b + l*768,
           q_buf, nullptr, 768, nullptr, nullptr, 784, 768, 768, 0);
      gemm(scene_bf, 768, rkv_w + (size_t)l*1536*768, 768, rkv_b + l*1536,
           kv_buf, nullptr, 1536, nullptr, nullptr, 4096, 1536, 768, 0);
      attn_kernel<<<B_*NH_, 256, 0, stream>>>(q_buf, 768, 0, 49,
          kv_buf, 1536, 0, 768, 256,
          l_cos, l_sin, N_*32, sc_cos, sc_sin, 0, act_bf);
      gemm(act_bf, 768, ro_w + (size_t)l*768*768, 768, ro_b + l*768,
           local_f, local_bf, 768, local_f, rgate + l*768, 784, 768, 768, 2);
      // ---- self attention ----
      ln_kernel<<<784, 256, 0, stream>>>(local_f, ln1_w + l*768, ln1_b + l*768, ln_bf);
      gemm(ln_bf, 768, qkv_w + (size_t)l*2304*768, 768, qkv_b + l*2304,
           kv_buf, nullptr, 2304, nullptr, nullptr, 784, 2304, 768, 0);
      attn_kernel<<<B_*NH_, 256, 0, stream>>>(kv_buf, 2304, 0, 49,
          kv_buf, 2304, 768, 1536, 49,
          l_cos, l_sin, N_*32, l_cos, l_sin, N_*32, act_bf);
      gemm(act_bf, 768, ao_w + (size_t)l*768*768, 768, ao_b + l*768,
           local_f, local_bf, 768, local_f, nullptr, 784, 768, 768, 2);
      // ---- MLP ----
      ln_kernel<<<784, 256, 0, stream>>>(local_f, ln2_w + l*768, ln2_b + l*768, ln_bf);
      gemm(ln_bf, 768, m1_w + (size_t)l*3072*768, 768, m1_b + l*3072,
           nullptr, act_bf, 3072, nullptr, nullptr, 784, 3072, 768, 1);
      gemm(act_bf, 3072, m2_w + (size_t)l*768*3072, 3072, m2_b + l*768,
           local_f, local_bf, 768, local_f, nullptr, 784, 768, 3072, 2);
      // ---- write cross (scene queries local) ----
      gemm(scene_bf, 768, wq_w + (size_t)l*768*768, 768, wq_b + l*768,
           q_buf, nullptr, 768, nullptr, nullptr, 4096, 768, 768, 0);
      gemm(local_bf, 768, wkv_w + (size_t)l*1536*768, 768, wkv_b + l*1536,
           kv_buf, nullptr, 1536, nullptr, nullptr, 784, 1536, 768, 0);
      attn_kernel<<<B_*NH_, 256, 0, stream>>>(q_buf, 768, 0, 256,
          kv_buf, 1536, 0, 768, 49,
          sc_cos, sc_sin, 0, l_cos, l_sin, N_*32, act_bf);
      gemm(act_bf, 768, wo_w + (size_t)l*768*768, 768, wo_b + l*768,
           scene_f, scene_bf, 768, scene_f, wgate + l*768, 4096, 768, 768, 2);
    }
  }
}

// Round 2
// 11956.119 us; speedup vs baseline: 2.3826x; 2.3826x over previous
//
#include <hip/hip_runtime.h>

#define B_ 16
#define V_ 2
#define G_ 7
#define PATCH_ 14
#define SG_ 16
#define D_ 768
#define NH_ 12
#define L_ 12
#define DH_ 64
#define N_ 49
#define S_ 256

__device__ __forceinline__ unsigned short f2bf(float f) {
  unsigned int u = __builtin_bit_cast(unsigned int, f);
  u += 0x7fffu + ((u >> 16) & 1u);
  return (unsigned short)(u >> 16);
}
__device__ __forceinline__ float bf2f(unsigned short h) {
  unsigned int u = ((unsigned int)h) << 16;
  return __builtin_bit_cast(float, u);
}

using bf16x8 = __attribute__((ext_vector_type(8))) __bf16;
using u16x8  = __attribute__((ext_vector_type(8))) unsigned short;
using f32x4  = __attribute__((ext_vector_type(4))) float;

#if defined(__has_builtin)
# if __has_builtin(__builtin_amdgcn_global_load_lds)
#  define HAVE_GLL 1
# endif
#endif

__device__ __forceinline__ void g2l16(const unsigned short* g, unsigned short* l) {
#ifdef HAVE_GLL
  __builtin_amdgcn_global_load_lds(
      (const __attribute__((address_space(1))) unsigned int*)g,
      (__attribute__((address_space(3))) unsigned int*)l, 16, 0, 0);
#else
  *(u16x8*)l = *(const u16x8*)g;
#endif
}

// ---------------------------------------------------------------- GEMM ----
// C(MxN) = A(MxK bf16 row-major) @ W(NxK bf16 row-major)^T + bias
// epi: 0=none, 1=gelu, 2=res+gate*val.  BK=64, 4 waves (2x2), m97 structure.
template <int BM, int BN>
__global__ __launch_bounds__(256) void gemm_bf_k(
    const unsigned short* __restrict__ A, int lda,
    const unsigned short* __restrict__ W, int ldw,
    const float* __restrict__ bias,
    float* __restrict__ Cf, unsigned short* __restrict__ Cb, int ldc,
    const float* __restrict__ res, const float* __restrict__ gate,
    int M, int N, int K, int epi)
{
  __shared__ unsigned short As[BM * 64];
  __shared__ unsigned short Bs[BN * 64];
  constexpr int FM = BM / 32, FN = BN / 32;
  const int m0 = blockIdx.x * BM, n0 = blockIdx.y * BN;
  const int tid = threadIdx.x, lane = tid & 63, wid = tid >> 6;
  const int wr = wid >> 1, wc = wid & 1;
  const int fr = lane & 15, kq = (lane >> 4) * 8;
  const int srow = tid >> 3, scol = (tid & 7) * 8;

  f32x4 acc[FM][FN];
#pragma unroll
  for (int mi = 0; mi < FM; ++mi)
#pragma unroll
    for (int ni = 0; ni < FN; ++ni) acc[mi][ni] = f32x4{0.f, 0.f, 0.f, 0.f};

  for (int k0 = 0; k0 < K; k0 += 64) {
    const unsigned short* ga = A + (size_t)(m0 + srow) * lda + k0 + scol;
    const unsigned short* gb = W + (size_t)(n0 + srow) * ldw + k0 + scol;
#pragma unroll
    for (int c = 0; c < BM / 32; ++c)
      g2l16(ga + (size_t)c * 32 * lda, &As[c * 2048 + tid * 8]);
#pragma unroll
    for (int c = 0; c < BN / 32; ++c)
      g2l16(gb + (size_t)c * 32 * ldw, &Bs[c * 2048 + tid * 8]);
    __syncthreads();
#pragma unroll
    for (int ks = 0; ks < 2; ++ks) {
      bf16x8 av[FM], bv[FN];
#pragma unroll
      for (int mi = 0; mi < FM; ++mi)
        av[mi] = __builtin_bit_cast(bf16x8,
            *(const u16x8*)&As[(wr * (BM / 2) + mi * 16 + fr) * 64 + ks * 32 + kq]);
#pragma unroll
      for (int ni = 0; ni < FN; ++ni)
        bv[ni] = __builtin_bit_cast(bf16x8,
            *(const u16x8*)&Bs[(wc * (BN / 2) + ni * 16 + fr) * 64 + ks * 32 + kq]);
#pragma unroll
      for (int mi = 0; mi < FM; ++mi)
#pragma unroll
        for (int ni = 0; ni < FN; ++ni)
          acc[mi][ni] = __builtin_amdgcn_mfma_f32_16x16x32_bf16(av[mi], bv[ni], acc[mi][ni], 0, 0, 0);
    }
    __syncthreads();
  }

  const int er = (lane >> 4) * 4, ec = lane & 15;
#pragma unroll
  for (int mi = 0; mi < FM; ++mi)
#pragma unroll
    for (int ni = 0; ni < FN; ++ni) {
      int gc = n0 + wc * (BN / 2) + ni * 16 + ec;
      float bi = bias ? bias[gc] : 0.0f;
      float gg = gate ? gate[gc] : 1.0f;
#pragma unroll
      for (int i = 0; i < 4; ++i) {
        int gr = m0 + wr * (BM / 2) + mi * 16 + er + i;
        if (gr < M) {
          float v = acc[mi][ni][i] + bi;
          if (epi == 1) {
            float xx = v;
            v = 0.5f * xx * (1.0f + tanhf(0.79788456080286536f * (xx + 0.044715f * xx * xx * xx)));
          } else if (epi == 2) {
            v = res[(size_t)gr * ldc + gc] + gg * v;
          }
          if (Cf) Cf[(size_t)gr * ldc + gc] = v;
          if (Cb) Cb[(size_t)gr * ldc + gc] = f2bf(v);
        }
      }
    }
}

// ----------------------------------------------------------- attention ----
// Block (b,h) x row-split. K/V fp32 in LDS; K chunk-XOR swizzled; 1/8 folded
// into K. Each wave handles rows r0+wid, +4, ...
__global__ __launch_bounds__(256) void attn_k(
    const float* __restrict__ Q, int ldq, int qoff, int Lq,
    const float* __restrict__ KV, int ldkv, int koff, int voff, int Lk,
    const float* __restrict__ cq, const float* __restrict__ sq, int rbq,
    const float* __restrict__ ck, const float* __restrict__ sk, int rbk,
    unsigned short* __restrict__ Out)
{
  __shared__ float Kf[S_ * DH_];
  __shared__ float Vf[S_ * DH_];
  __shared__ float qsh[4][DH_];
  __shared__ float pbuf[4][S_];
  const int b = blockIdx.x / NH_, h = blockIdx.x - b * NH_;
  const int tid = threadIdx.x, lane = tid & 63, wid = tid >> 6;

  for (int idx = tid; idx < Lk * 32; idx += 256) {
    int t = idx >> 5, m = idx & 31;
    size_t rowb = ((size_t)b * Lk + t) * ldkv;
    const float* kr = KV + rowb + koff + h * DH_;
    const float* vr = KV + rowb + voff + h * DH_;
    float k1 = kr[2 * m], k2 = kr[2 * m + 1];
    size_t ri = (size_t)b * rbk + (size_t)t * 32 + m;
    float c = ck[ri], s = sk[ri];
    int ch = (m >> 1) ^ (t & 15);
    int kb = (t << 6) + (ch << 2) + ((m & 1) << 1);
    Kf[kb]     = (k1 * c - k2 * s) * 0.125f;
    Kf[kb + 1] = (k1 * s + k2 * c) * 0.125f;
    Vf[(t << 6) + 2 * m]     = vr[2 * m];
    Vf[(t << 6) + 2 * m + 1] = vr[2 * m + 1];
  }
  __syncthreads();

  const int nt = (Lk + 63) >> 6;
  const int nspl = gridDim.y;
  const int rows = (Lq + nspl - 1) / nspl;
  const int r0 = blockIdx.y * rows;
  const int r1 = (Lq < r0 + rows) ? Lq : (r0 + rows);

  for (int r = r0 + wid; r < r1; r += 4) {
    float x = Q[((size_t)b * Lq + r) * ldq + qoff + h * DH_ + lane];
    float px = __shfl_xor(x, 1);
    size_t ri = (size_t)b * rbq + (size_t)r * 32 + (lane >> 1);
    float c = cq[ri], s = sq[ri];
    float qr = (lane & 1) ? (px * s + x * c) : (x * c - px * s);
    qsh[wid][lane] = qr;
    __asm__ volatile("s_waitcnt lgkmcnt(0)" ::: "memory");
    f32x4 qv[16];
#pragma unroll
    for (int cc = 0; cc < 16; ++cc) qv[cc] = *(const f32x4*)&qsh[wid][cc * 4];

    float sc0 = -1e30f, sc1 = -1e30f, sc2 = -1e30f, sc3 = -1e30f;
#pragma unroll
    for (int j = 0; j < 4; ++j) {
      if (j < nt) {
        int t = lane + (j << 6);
        if (t < Lk) {
          int sw = t & 15;
          const float* kp = &Kf[t << 6];
          float a0 = 0.f, a1 = 0.f, a2 = 0.f, a3 = 0.f;
#pragma unroll
          for (int cc = 0; cc < 16; ++cc) {
            f32x4 kv = *(const f32x4*)(kp + ((cc ^ sw) << 2));
            a0 += qv[cc].x * kv.x; a1 += qv[cc].y * kv.y;
            a2 += qv[cc].z * kv.z; a3 += qv[cc].w * kv.w;
          }
          float v = (a0 + a1) + (a2 + a3);
          if (j == 0) sc0 = v; else if (j == 1) sc1 = v; else if (j == 2) sc2 = v; else sc3 = v;
        }
      }
    }
    float mx = fmaxf(fmaxf(sc0, sc1), fmaxf(sc2, sc3));
    for (int o = 32; o; o >>= 1) mx = fmaxf(mx, __shfl_xor(mx, o));
    float sum;
    { float e = expf(sc0 - mx); pbuf[wid][lane] = e; sum = e; }
    if (nt > 1) { float e = expf(sc1 - mx); pbuf[wid][lane + 64]  = e; sum += e; }
    if (nt > 2) { float e = expf(sc2 - mx); pbuf[wid][lane + 128] = e; sum += e; }
    if (nt > 3) { float e = expf(sc3 - mx); pbuf[wid][lane + 192] = e; sum += e; }
    for (int o = 32; o; o >>= 1) sum += __shfl_xor(sum, o);
    float inv = 1.0f / sum;

    float o0 = 0.f, o1 = 0.f, o2 = 0.f, o3 = 0.f;
    int t = 0;
    for (; t + 3 < Lk; t += 4) {
      o0 += pbuf[wid][t]     * Vf[((t)     << 6) + lane];
      o1 += pbuf[wid][t + 1] * Vf[((t + 1) << 6) + lane];
      o2 += pbuf[wid][t + 2] * Vf[((t + 2) << 6) + lane];
      o3 += pbuf[wid][t + 3] * Vf[((t + 3) << 6) + lane];
    }
    for (; t < Lk; ++t) o0 += pbuf[wid][t] * Vf[(t << 6) + lane];
    float od = (o0 + o1) + (o2 + o3);
    Out[((size_t)b * Lq + r) * D_ + h * DH_ + lane] = f2bf(od * inv);
  }
}

// ----------------------------------------------------------- layernorm ----
__global__ __launch_bounds__(256) void ln_kernel(
    const float* __restrict__ X, const float* __restrict__ w,
    const float* __restrict__ bsh, unsigned short* __restrict__ Out)
{
  const int row = blockIdx.x, tid = threadIdx.x;
  const float* x = X + (size_t)row * D_;
  float v0 = x[tid], v1 = x[tid + 256], v2 = x[tid + 512];
  __shared__ float red[4];
  float s = v0 + v1 + v2;
  for (int o = 32; o; o >>= 1) s += __shfl_xor(s, o);
  if ((tid & 63) == 0) red[tid >> 6] = s;
  __syncthreads();
  float mean = (red[0] + red[1] + red[2] + red[3]) * (1.0f / 768.0f);
  float d0 = v0 - mean, d1 = v1 - mean, d2 = v2 - mean;
  float q = d0 * d0 + d1 * d1 + d2 * d2;
  __syncthreads();
  for (int o = 32; o; o >>= 1) q += __shfl_xor(q, o);
  if ((tid & 63) == 0) red[tid >> 6] = q;
  __syncthreads();
  float var = (red[0] + red[1] + red[2] + red[3]) * (1.0f / 768.0f);
  float rstd = rsqrtf(var + 1e-6f);
  Out[(size_t)row * D_ + tid]       = f2bf(d0 * rstd * w[tid]       + bsh[tid]);
  Out[(size_t)row * D_ + tid + 256] = f2bf(d1 * rstd * w[tid + 256] + bsh[tid + 256]);
  Out[(size_t)row * D_ + tid + 512] = f2bf(d2 * rstd * w[tid + 512] + bsh[tid + 512]);
}

// ------------------------------------------------------ weight convert ----
struct Cvt10 {
  const float* s[10];
  unsigned short* d[10];
  int blkEnd[10];
};
__global__ __launch_bounds__(256) void cvt_multi_k(Cvt10 c) {
  int bid = blockIdx.x;
  int seg = 0;
#pragma unroll
  for (int i = 0; i < 9; ++i) seg += (bid >= c.blkEnd[i]) ? 1 : 0;
  int lb = bid - (seg ? c.blkEnd[seg - 1] : 0);
  size_t off = ((size_t)lb * 256 + threadIdx.x) * 8;
  const float* s = c.s[seg] + off;
  f32x4 a = *(const f32x4*)s, b2 = *(const f32x4*)(s + 4);
  u16x8 o;
  o[0] = f2bf(a.x); o[1] = f2bf(a.y); o[2] = f2bf(a.z); o[3] = f2bf(a.w);
  o[4] = f2bf(b2.x); o[5] = f2bf(b2.y); o[6] = f2bf(b2.z); o[7] = f2bf(b2.w);
  *(u16x8*)(c.d[seg] + off) = o;
}

__global__ void cvt_patch_k(const float* __restrict__ s, unsigned short* __restrict__ d) {
  int i = blockIdx.x * 256 + threadIdx.x;
  if (i >= 768 * 640) return;
  int r = i / 640, col = i - r * 640;
  d[i] = f2bf(col < 588 ? s[r * 588 + col] : 0.0f);
}

// --------------------------------------------------------------- misc ----
__global__ void init_scene_k(const float* __restrict__ tok, float* __restrict__ sf,
                             unsigned short* __restrict__ sb, int total) {
  int i = blockIdx.x * 256 + threadIdx.x;
  if (i < total) {
    float v = tok[i % (S_ * D_)];
    sf[i] = v; sb[i] = f2bf(v);
  }
}

__global__ void rope_scene_k(float* __restrict__ c, float* __restrict__ s) {
  int idx = blockIdx.x * 256 + threadIdx.x;
  if (idx >= S_ * 32) return;
  int t = idx >> 5, m = idx & 31;
  int i = t >> 4, j = t & 15;
  float xx = -1.0f + 2.0f * j / 15.0f;
  float yy = -1.0f + 2.0f * i / 15.0f;
  float coord = (m < 16) ? xx : yy;
  float per = powf(100.0f, (float)(m & 15) / 16.0f);
  float ang = coord / per;
  c[idx] = cosf(ang); s[idx] = sinf(ang);
}

__global__ void rope_local_k(float* __restrict__ c, float* __restrict__ s,
                             const float* __restrict__ ctr, const float* __restrict__ scl) {
  int idx = blockIdx.x * 256 + threadIdx.x;
  if (idx >= B_ * N_ * 32) return;
  int b = idx / (N_ * 32);
  int r = idx - b * (N_ * 32);
  int pch = r >> 5, m = r & 31;
  int py = pch / 7, px = pch - py * 7;
  float cx = ctr[b * 2], cy = ctr[b * 2 + 1], sc = scl[b];
  float gx = cx + sc * ((px - 3.0f) / 3.0f);
  float gy = cy + sc * ((py - 3.0f) / 3.0f);
  float coord = (m < 16) ? gx : gy;
  float per = powf(100.0f, (float)(m & 15) / 16.0f);
  float ang = coord / per;
  c[idx] = cosf(ang); s[idx] = sinf(ang);
}

// bilinear glimpse sample -> im2col row (b*49+p), K padded to 640
__global__ void im2col_k(unsigned short* __restrict__ xb, const float* __restrict__ img,
                         const float* __restrict__ ctr, const float* __restrict__ scl) {
  int idx = blockIdx.x * 256 + threadIdx.x;
  if (idx >= 784 * 640) return;
  int row = idx / 640, col = idx - row * 640;
  float val = 0.0f;
  if (col < 588) {
    int b = row / 49, pch = row - b * 49;
    int c = col / 196, rr = col - c * 196;
    int i = rr / 14, j = rr - i * 14;
    int py = pch / 7, px = pch - py * 7;
    int gyi = py * 14 + i, gxi = px * 14 + j;
    float cx = ctr[b * 2], cy = ctr[b * 2 + 1], sc = scl[b];
    float gy = cy + sc * (-1.0f + 2.0f * gyi / 97.0f);
    float gx = cx + sc * (-1.0f + 2.0f * gxi / 97.0f);
    float pyi = (gy + 1.0f) * 0.5f * 223.0f;
    float pxi = (gx + 1.0f) * 0.5f * 223.0f;
    float y0f = fminf(fmaxf(floorf(pyi), 0.0f), 222.0f);
    float x0f = fminf(fmaxf(floorf(pxi), 0.0f), 222.0f);
    int y0 = (int)y0f, x0 = (int)x0f;
    float wy = fminf(fmaxf(pyi - y0f, 0.0f), 1.0f);
    float wx = fminf(fmaxf(pxi - x0f, 0.0f), 1.0f);
    const float* base = img + (size_t)(b * 3 + c) * 224 * 224;
    float v00 = base[y0 * 224 + x0],       v01 = base[y0 * 224 + x0 + 1];
    float v10 = base[(y0 + 1) * 224 + x0], v11 = base[(y0 + 1) * 224 + x0 + 1];
    val = (v00 * (1.0f - wy) + v10 * wy) * (1.0f - wx) + (v01 * (1.0f - wy) + v11 * wy) * wx;
  }
  xb[idx] = f2bf(val);
}

// -------------------------------------------------------------- launch ----
extern "C" void kernel_launch(void* const* d_in, const int* in_sizes, int n_in,
                              void* d_out, int out_size, void* d_ws, size_t ws_size,
                              hipStream_t stream) {
  const float* images    = (const float*)d_in[0];
  const float* centers   = (const float*)d_in[1];
  const float* scales    = (const float*)d_in[2];
  const float* patch_w   = (const float*)d_in[3];
  const float* patch_b   = (const float*)d_in[4];
  const float* scene_tok = (const float*)d_in[5];
  const float* ln1_w = (const float*)d_in[6];
  const float* ln1_b = (const float*)d_in[7];
  const float* ln2_w = (const float*)d_in[8];
  const float* ln2_b = (const float*)d_in[9];
  const float* qkv_w = (const float*)d_in[10];
  const float* qkv_b = (const float*)d_in[11];
  const float* ao_w  = (const float*)d_in[12];
  const float* ao_b  = (const float*)d_in[13];
  const float* m1_w  = (const float*)d_in[14];
  const float* m1_b  = (const float*)d_in[15];
  const float* m2_w  = (const float*)d_in[16];
  const float* m2_b  = (const float*)d_in[17];
  const float* rq_w  = (const float*)d_in[18];
  const float* rq_b  = (const float*)d_in[19];
  const float* rkv_w = (const float*)d_in[20];
  const float* rkv_b = (const float*)d_in[21];
  const float* ro_w  = (const float*)d_in[22];
  const float* ro_b  = (const float*)d_in[23];
  const float* rgate = (const float*)d_in[24];
  const float* wq_w  = (const float*)d_in[25];
  const float* wq_b  = (const float*)d_in[26];
  const float* wkv_w = (const float*)d_in[27];
  const float* wkv_b = (const float*)d_in[28];
  const float* wo_w  = (const float*)d_in[29];
  const float* wo_b  = (const float*)d_in[30];
  const float* wgate = (const float*)d_in[31];

  float* scene_f = (float*)d_out;

  char* p = (char*)d_ws;
  auto alloc = [&](size_t bytes) { char* r = p; p += (bytes + 255) & ~(size_t)255; return (void*)r; };
  unsigned short* scene_bf = (unsigned short*)alloc((size_t)4096 * 768 * 2);
  float*          local_f  = (float*)alloc((size_t)784 * 768 * 4);
  unsigned short* local_bf = (unsigned short*)alloc((size_t)832 * 768 * 2);
  float*          q_r      = (float*)alloc((size_t)784 * 768 * 4);
  float*          q_buf    = (float*)alloc((size_t)4096 * 768 * 4);
  float*          kv_buf   = (float*)alloc((size_t)4096 * 1536 * 4);
  unsigned short* ln_bf    = (unsigned short*)alloc((size_t)832 * 768 * 2);
  unsigned short* act_bf   = (unsigned short*)alloc((size_t)4096 * 768 * 2);
  unsigned short* x_bf     = (unsigned short*)alloc((size_t)832 * 640 * 2);
  float* sc_cos = (float*)alloc((size_t)S_ * 32 * 4);
  float* sc_sin = (float*)alloc((size_t)S_ * 32 * 4);
  float* l_cos  = (float*)alloc((size_t)B_ * N_ * 32 * 4);
  float* l_sin  = (float*)alloc((size_t)B_ * N_ * 32 * 4);
  unsigned short* patch_wbf = (unsigned short*)alloc((size_t)768 * 640 * 2);

  // weight tensor table: rq, rkv, ro, qkv, ao, m1, m2, wq, wkv, wo
  static const size_t WSZ[10] = {589824, 1179648, 589824, 1769472, 589824,
                                 2359296, 2359296, 589824, 1179648, 589824};
  const float* WSRC[10] = {rq_w, rkv_w, ro_w, qkv_w, ao_w, m1_w, m2_w, wq_w, wkv_w, wo_w};
  size_t cumL[11]; cumL[0] = 0;
  for (int i = 0; i < 10; ++i) cumL[i + 1] = cumL[i] + WSZ[i];
  const size_t perLayer = cumL[10];                  // 11,796,480
  const size_t allElems = perLayer * L_;             // 141,557,760
  size_t usedBytes = (size_t)(p - (char*)d_ws);
  bool preconv = ws_size >= usedBytes + allElems * 2 + 4096;
  unsigned short* wbf = (unsigned short*)alloc((preconv ? allElems : perLayer) * 2);

  auto G = [&](int BM, const unsigned short* A, int lda, const unsigned short* Wp, int ldw,
               const float* bias, float* Cf, unsigned short* Cb, int ldc,
               const float* res, const float* gt, int M, int N, int K, int epi) {
    if (BM == 128)
      gemm_bf_k<128, 128><<<dim3(M / 128, N / 128), 256, 0, stream>>>(
          A, lda, Wp, ldw, bias, Cf, Cb, ldc, res, gt, M, N, K, epi);
    else
      gemm_bf_k<64, 64><<<dim3((M + 63) / 64, N / 64), 256, 0, stream>>>(
          A, lda, Wp, ldw, bias, Cf, Cb, ldc, res, gt, M, N, K, epi);
  };

  {
    int total = B_ * S_ * D_;
    init_scene_k<<<(total + 255) / 256, 256, 0, stream>>>(scene_tok, scene_f, scene_bf, total);
    rope_scene_k<<<(S_ * 32 + 255) / 256, 256, 0, stream>>>(sc_cos, sc_sin);
    cvt_patch_k<<<(768 * 640 + 255) / 256, 256, 0, stream>>>(patch_w, patch_wbf);
    if (preconv) {
      Cvt10 cv;
      int blk = 0;
      size_t dof = 0;
      for (int i = 0; i < 10; ++i) {
        cv.s[i] = WSRC[i];
        cv.d[i] = wbf + dof;
        blk += (int)(WSZ[i] * L_ / 2048);
        cv.blkEnd[i] = blk;
        dof += WSZ[i] * L_;
      }
      cvt_multi_k<<<blk, 256, 0, stream>>>(cv);
    }
  }

  for (int vp = 0; vp < V_; ++vp) {
    const float* ctr = centers + (size_t)vp * B_ * 2;
    const float* scl = scales + (size_t)vp * B_;
    rope_local_k<<<(B_ * N_ * 32 + 255) / 256, 256, 0, stream>>>(l_cos, l_sin, ctr, scl);
    im2col_k<<<(784 * 640 + 255) / 256, 256, 0, stream>>>(x_bf, images, ctr, scl);
    G(64, x_bf, 640, patch_wbf, 640, patch_b, local_f, local_bf, 768,
      nullptr, nullptr, 784, 768, 640, 0);

    for (int l = 0; l < L_; ++l) {
      const unsigned short* w10[10];
      if (preconv) {
        size_t dof = 0;
        for (int i = 0; i < 10; ++i) { w10[i] = wbf + dof + (size_t)l * WSZ[i]; dof += WSZ[i] * L_; }
      } else {
        Cvt10 cv;
        int blk = 0;
        for (int i = 0; i < 10; ++i) {
          cv.s[i] = WSRC[i] + (size_t)l * WSZ[i];
          cv.d[i] = wbf + cumL[i];
          w10[i] = wbf + cumL[i];
          blk += (int)(WSZ[i] / 2048);
          cv.blkEnd[i] = blk;
        }
        cvt_multi_k<<<blk, 256, 0, stream>>>(cv);
      }

      // ---- independent: wq (scene), rkv (scene), rq (local) ----
      G(128, scene_bf, 768, w10[7], 768, wq_b + l * 768,
        q_buf, nullptr, 768, nullptr, nullptr, 4096, 768, 768, 0);
      G(128, scene_bf, 768, w10[1], 768, rkv_b + (size_t)l * 1536,
        kv_buf, nullptr, 1536, nullptr, nullptr, 4096, 1536, 768, 0);
      G(64, local_bf, 768, w10[0], 768, rq_b + l * 768,
        q_r, nullptr, 768, nullptr, nullptr, 784, 768, 768, 0);
      // ---- read cross ----
      attn_k<<<dim3(B_ * NH_, 2), 256, 0, stream>>>(q_r, 768, 0, 49,
          kv_buf, 1536, 0, 768, 256, l_cos, l_sin, N_ * 32, sc_cos, sc_sin, 0, act_bf);
      G(64, act_bf, 768, w10[2], 768, ro_b + l * 768,
        local_f, local_bf, 768, local_f, rgate + l * 768, 784, 768, 768, 2);
      // ---- self attention ----
      ln_kernel<<<784, 256, 0, stream>>>(local_f, ln1_w + l * 768, ln1_b + l * 768, ln_bf);
      G(64, ln_bf, 768, w10[3], 768, qkv_b + (size_t)l * 2304,
        kv_buf, nullptr, 2304, nullptr, nullptr, 784, 2304, 768, 0);
      attn_k<<<dim3(B_ * NH_, 1), 256, 0, stream>>>(kv_buf, 2304, 0, 49,
          kv_buf, 2304, 768, 1536, 49, l_cos, l_sin, N_ * 32, l_cos, l_sin, N_ * 32, act_bf);
      G(64, act_bf, 768, w10[4], 768, ao_b + l * 768,
        local_f, local_bf, 768, local_f, nullptr, 784, 768, 768, 2);
      // ---- MLP ----
      ln_kernel<<<784, 256, 0, stream>>>(local_f, ln2_w + l * 768, ln2_b + l * 768, ln_bf);
      G(64, ln_bf, 768, w10[5], 768, m1_b + (size_t)l * 3072,
        nullptr, act_bf, 3072, nullptr, nullptr, 784, 3072, 768, 1);
      G(64, act_bf, 3072, w10[6], 3072, m2_b + l * 768,
        local_f, local_bf, 768, local_f, nullptr, 784, 768, 3072, 2);
      // ---- write cross ----
      G(64, local_bf, 768, w10[8], 768, wkv_b + (size_t)l * 1536,
        kv_buf, nullptr, 1536, nullptr, nullptr, 784, 1536, 768, 0);
      attn_k<<<dim3(B_ * NH_, 4), 256, 0, stream>>>(q_buf, 768, 0, 256,
          kv_buf, 1536, 0, 768, 49, sc_cos, sc_sin, 0, l_cos, l_sin, N_ * 32, act_bf);
      G(128, act_bf, 768, w10[9], 768, wo_b + l * 768,
        scene_f, scene_bf, 768, scene_f, wgate + l * 768, 4096, 768, 768, 2);
    }
  }
}

// Round 4
// 10730.217 us; speedup vs baseline: 2.6548x; 1.1142x over previous
//
#include <hip/hip_runtime.h>

#define B_ 16
#define V_ 2
#define D_ 768
#define NH_ 12
#define L_ 12
#define DH_ 64
#define N_ 49
#define S_ 256

__device__ __forceinline__ unsigned short f2bf(float f) {
  unsigned int u = __builtin_bit_cast(unsigned int, f);
  u += 0x7fffu + ((u >> 16) & 1u);
  return (unsigned short)(u >> 16);
}
__device__ __forceinline__ float bf2f(unsigned short h) {
  unsigned int u = ((unsigned int)h) << 16;
  return __builtin_bit_cast(float, u);
}

using bf16x8 = __attribute__((ext_vector_type(8))) __bf16;
using u16x8  = __attribute__((ext_vector_type(8))) unsigned short;
using f32x4  = __attribute__((ext_vector_type(4))) float;

__device__ __forceinline__ void g2l16(const unsigned short* g, unsigned short* l) {
  __builtin_amdgcn_global_load_lds(
      (const __attribute__((address_space(1))) unsigned int*)g,
      (__attribute__((address_space(3))) unsigned int*)l, 16, 0, 0);
}

// ---------------------------------------------------------------- GEMM ----
// C(MxN) = A(MxK bf16 rm) @ W(NxK bf16 rm)^T + bias. Prefetched dbuf K-loop,
// XOR-swizzled LDS (slot ^= row&7, 16B slots), 4 waves 2x2.
// epi: 0=none, 1=gelu, 2=res+gate*val
template <int BM, int BN, int BK>
__global__ __launch_bounds__(256) void gemm_v3(
    const unsigned short* __restrict__ A, int lda,
    const unsigned short* __restrict__ W, int ldw,
    const float* __restrict__ bias,
    float* __restrict__ Cf, unsigned short* __restrict__ Cb, int ldc,
    const float* __restrict__ res, const float* __restrict__ gate,
    int M, int N, int K, int epi)
{
  __shared__ unsigned short As[2][BM * BK];
  __shared__ unsigned short Bs[2][BN * BK];
  constexpr int FM = BM / 32, FN = BN / 32;   // frags per wave (2x2 waves)
  constexpr int CPR = BK / 8;                  // 16B chunks per row
  const int m0 = blockIdx.x * BM, n0 = blockIdx.y * BN;
  const int tid = threadIdx.x, lane = tid & 63, wid = tid >> 6;
  const int wr = wid >> 1, wc = wid & 1;
  const int fr = lane & 15, kq8 = lane >> 4;

  f32x4 acc[FM][FN];
#pragma unroll
  for (int mi = 0; mi < FM; ++mi)
#pragma unroll
    for (int ni = 0; ni < FN; ++ni) acc[mi][ni] = f32x4{0.f, 0.f, 0.f, 0.f};

  auto stage = [&](int buf, int k0) {
    const unsigned short* Ab = A + (size_t)m0 * lda + k0;
    const unsigned short* Bb = W + (size_t)n0 * ldw + k0;
#pragma unroll
    for (int ra = 0; ra < BM * BK / 2048; ++ra) {
      int c = ra * 256 + tid;
      int row = c / CPR, slot = c % CPR;
      int gslot = slot ^ (row & 7);
      g2l16(Ab + (size_t)row * lda + gslot * 8, &As[buf][c * 8]);
    }
#pragma unroll
    for (int rb = 0; rb < BN * BK / 2048; ++rb) {
      int c = rb * 256 + tid;
      int row = c / CPR, slot = c % CPR;
      int gslot = slot ^ (row & 7);
      g2l16(Bb + (size_t)row * ldw + gslot * 8, &Bs[buf][c * 8]);
    }
  };

  const int nt = K / BK;
  stage(0, 0);
  __asm__ volatile("s_waitcnt vmcnt(0) lgkmcnt(0)" ::: "memory");
  __builtin_amdgcn_s_barrier();
  __builtin_amdgcn_sched_barrier(0);

  int cur = 0;
  for (int t = 0; t < nt; ++t) {
    if (t + 1 < nt) stage(cur ^ 1, (t + 1) * BK);
#pragma unroll
    for (int ks = 0; ks < BK / 32; ++ks) {
      bf16x8 av[FM], bv[FN];
#pragma unroll
      for (int mi = 0; mi < FM; ++mi) {
        int row = wr * (BM / 2) + mi * 16 + fr;
        int idx = row * BK + (((ks * 4 + kq8) ^ (row & 7)) << 3);
        av[mi] = __builtin_bit_cast(bf16x8, *(const u16x8*)&As[cur][idx]);
      }
#pragma unroll
      for (int ni = 0; ni < FN; ++ni) {
        int row = wc * (BN / 2) + ni * 16 + fr;
        int idx = row * BK + (((ks * 4 + kq8) ^ (row & 7)) << 3);
        bv[ni] = __builtin_bit_cast(bf16x8, *(const u16x8*)&Bs[cur][idx]);
      }
#pragma unroll
      for (int mi = 0; mi < FM; ++mi)
#pragma unroll
        for (int ni = 0; ni < FN; ++ni)
          acc[mi][ni] = __builtin_amdgcn_mfma_f32_16x16x32_bf16(av[mi], bv[ni], acc[mi][ni], 0, 0, 0);
    }
    __asm__ volatile("s_waitcnt vmcnt(0) lgkmcnt(0)" ::: "memory");
    __builtin_amdgcn_s_barrier();
    __builtin_amdgcn_sched_barrier(0);
    cur ^= 1;
  }

  const int er = (lane >> 4) * 4, ec = lane & 15;
#pragma unroll
  for (int mi = 0; mi < FM; ++mi)
#pragma unroll
    for (int ni = 0; ni < FN; ++ni) {
      int gc = n0 + wc * (BN / 2) + ni * 16 + ec;
      float bi = bias ? bias[gc] : 0.0f;
      float gg = gate ? gate[gc] : 1.0f;
#pragma unroll
      for (int i = 0; i < 4; ++i) {
        int gr = m0 + wr * (BM / 2) + mi * 16 + er + i;
        if (gr < M) {
          float v = acc[mi][ni][i] + bi;
          if (epi == 1) {
            v = v / (1.0f + __expf(-1.59576912f * (v + 0.044715f * v * v * v)));
          } else if (epi == 2) {
            v = res[(size_t)gr * ldc + gc] + gg * v;
          }
          if (Cf) Cf[(size_t)gr * ldc + gc] = v;
          if (Cb) Cb[(size_t)gr * ldc + gc] = f2bf(v);
        }
      }
    }
}

// ----------------------------------------------------------- attention ----
__global__ __launch_bounds__(256) void attn_k(
    const float* __restrict__ Q, int ldq, int qoff, int Lq,
    const float* __restrict__ KV, int ldkv, int koff, int voff, int Lk,
    const float* __restrict__ cq, const float* __restrict__ sq, int rbq,
    const float* __restrict__ ck, const float* __restrict__ sk, int rbk,
    unsigned short* __restrict__ Out)
{
  __shared__ float Kf[S_ * DH_];
  __shared__ float Vf[S_ * DH_];
  __shared__ float qsh[4][DH_];
  __shared__ float pbuf[4][S_];
  const int b = blockIdx.x / NH_, h = blockIdx.x - b * NH_;
  const int tid = threadIdx.x, lane = tid & 63, wid = tid >> 6;

  for (int idx = tid; idx < Lk * 32; idx += 256) {
    int t = idx >> 5, m = idx & 31;
    size_t rowb = ((size_t)b * Lk + t) * ldkv;
    const float* kr = KV + rowb + koff + h * DH_;
    const float* vr = KV + rowb + voff + h * DH_;
    float k1 = kr[2 * m], k2 = kr[2 * m + 1];
    size_t ri = (size_t)b * rbk + (size_t)t * 32 + m;
    float c = ck[ri], s = sk[ri];
    int ch = (m >> 1) ^ (t & 15);
    int kb = (t << 6) + (ch << 2) + ((m & 1) << 1);
    Kf[kb]     = (k1 * c - k2 * s) * 0.125f;
    Kf[kb + 1] = (k1 * s + k2 * c) * 0.125f;
    Vf[(t << 6) + 2 * m]     = vr[2 * m];
    Vf[(t << 6) + 2 * m + 1] = vr[2 * m + 1];
  }
  __syncthreads();

  const int nt = (Lk + 63) >> 6;
  const int nspl = gridDim.y;
  const int rows = (Lq + nspl - 1) / nspl;
  const int r0 = blockIdx.y * rows;
  const int r1 = (Lq < r0 + rows) ? Lq : (r0 + rows);

  for (int r = r0 + wid; r < r1; r += 4) {
    float x = Q[((size_t)b * Lq + r) * ldq + qoff + h * DH_ + lane];
    float px = __shfl_xor(x, 1);
    size_t ri = (size_t)b * rbq + (size_t)r * 32 + (lane >> 1);
    float c = cq[ri], s = sq[ri];
    float qr = (lane & 1) ? (px * s + x * c) : (x * c - px * s);
    qsh[wid][lane] = qr;
    __asm__ volatile("s_waitcnt lgkmcnt(0)" ::: "memory");
    f32x4 qv[16];
#pragma unroll
    for (int cc = 0; cc < 16; ++cc) qv[cc] = *(const f32x4*)&qsh[wid][cc * 4];

    float sc0 = -1e30f, sc1 = -1e30f, sc2 = -1e30f, sc3 = -1e30f;
#pragma unroll
    for (int j = 0; j < 4; ++j) {
      if (j < nt) {
        int t = lane + (j << 6);
        if (t < Lk) {
          int sw = t & 15;
          const float* kp = &Kf[t << 6];
          float a0 = 0.f, a1 = 0.f, a2 = 0.f, a3 = 0.f;
#pragma unroll
          for (int cc = 0; cc < 16; ++cc) {
            f32x4 kv = *(const f32x4*)(kp + ((cc ^ sw) << 2));
            a0 += qv[cc].x * kv.x; a1 += qv[cc].y * kv.y;
            a2 += qv[cc].z * kv.z; a3 += qv[cc].w * kv.w;
          }
          float v = (a0 + a1) + (a2 + a3);
          if (j == 0) sc0 = v; else if (j == 1) sc1 = v; else if (j == 2) sc2 = v; else sc3 = v;
        }
      }
    }
    float mx = fmaxf(fmaxf(sc0, sc1), fmaxf(sc2, sc3));
    for (int o = 32; o; o >>= 1) mx = fmaxf(mx, __shfl_xor(mx, o));
    float sum;
    { float e = __expf(sc0 - mx); pbuf[wid][lane] = e; sum = e; }
    if (nt > 1) { float e = __expf(sc1 - mx); pbuf[wid][lane + 64]  = e; sum += e; }
    if (nt > 2) { float e = __expf(sc2 - mx); pbuf[wid][lane + 128] = e; sum += e; }
    if (nt > 3) { float e = __expf(sc3 - mx); pbuf[wid][lane + 192] = e; sum += e; }
    for (int o = 32; o; o >>= 1) sum += __shfl_xor(sum, o);
    float inv = 1.0f / sum;

    float o0 = 0.f, o1 = 0.f, o2 = 0.f, o3 = 0.f;
    int t = 0;
    for (; t + 3 < Lk; t += 4) {
      o0 += pbuf[wid][t]     * Vf[((t)     << 6) + lane];
      o1 += pbuf[wid][t + 1] * Vf[((t + 1) << 6) + lane];
      o2 += pbuf[wid][t + 2] * Vf[((t + 2) << 6) + lane];
      o3 += pbuf[wid][t + 3] * Vf[((t + 3) << 6) + lane];
    }
    for (; t < Lk; ++t) o0 += pbuf[wid][t] * Vf[(t << 6) + lane];
    float od = (o0 + o1) + (o2 + o3);
    Out[((size_t)b * Lq + r) * D_ + h * DH_ + lane] = f2bf(od * inv);
  }
}

// ----------------------------------------------------------- layernorm ----
__global__ __launch_bounds__(256) void ln_kernel(
    const float* __restrict__ X, const float* __restrict__ w,
    const float* __restrict__ bsh, unsigned short* __restrict__ Out)
{
  const int row = blockIdx.x, tid = threadIdx.x;
  const float* x = X + (size_t)row * D_;
  float v0 = x[tid], v1 = x[tid + 256], v2 = x[tid + 512];
  __shared__ float red[4];
  float s = v0 + v1 + v2;
  for (int o = 32; o; o >>= 1) s += __shfl_xor(s, o);
  if ((tid & 63) == 0) red[tid >> 6] = s;
  __syncthreads();
  float mean = (red[0] + red[1] + red[2] + red[3]) * (1.0f / 768.0f);
  float d0 = v0 - mean, d1 = v1 - mean, d2 = v2 - mean;
  float q = d0 * d0 + d1 * d1 + d2 * d2;
  __syncthreads();
  for (int o = 32; o; o >>= 1) q += __shfl_xor(q, o);
  if ((tid & 63) == 0) red[tid >> 6] = q;
  __syncthreads();
  float var = (red[0] + red[1] + red[2] + red[3]) * (1.0f / 768.0f);
  float rstd = rsqrtf(var + 1e-6f);
  Out[(size_t)row * D_ + tid]       = f2bf(d0 * rstd * w[tid]       + bsh[tid]);
  Out[(size_t)row * D_ + tid + 256] = f2bf(d1 * rstd * w[tid + 256] + bsh[tid + 256]);
  Out[(size_t)row * D_ + tid + 512] = f2bf(d2 * rstd * w[tid + 512] + bsh[tid + 512]);
}

// ------------------------------------------------------ weight convert ----
// dst index = (e/lsrc)*lstride + (e%lsrc), dst base includes fused offset.
struct CvtA {
  const float* s[10];
  unsigned short* d[10];
  unsigned int lsrc[10];
  unsigned int lstride[10];
  int blkEnd[10];
};
__global__ __launch_bounds__(256) void cvt_multi_k(CvtA c) {
  int bid = blockIdx.x;
  int seg = 0;
#pragma unroll
  for (int i = 0; i < 9; ++i) seg += (bid >= c.blkEnd[i]) ? 1 : 0;
  unsigned int e = (unsigned int)(bid - (seg ? c.blkEnd[seg - 1] : 0)) * 2048u
                   + (unsigned int)threadIdx.x * 8u;
  unsigned int l = e / c.lsrc[seg], r = e - l * c.lsrc[seg];
  const float* s = c.s[seg] + e;
  unsigned short* d = c.d[seg] + (size_t)l * c.lstride[seg] + r;
  f32x4 a = *(const f32x4*)s, b2 = *(const f32x4*)(s + 4);
  u16x8 o;
  o[0] = f2bf(a.x); o[1] = f2bf(a.y); o[2] = f2bf(a.z); o[3] = f2bf(a.w);
  o[4] = f2bf(b2.x); o[5] = f2bf(b2.y); o[6] = f2bf(b2.z); o[7] = f2bf(b2.w);
  *(u16x8*)d = o;
}

__global__ void cvt_patch_k(const float* __restrict__ s, unsigned short* __restrict__ d) {
  int i = blockIdx.x * 256 + threadIdx.x;
  if (i >= 768 * 768) return;
  int r = i / 768, col = i - r * 768;
  d[i] = f2bf(col < 588 ? s[r * 588 + col] : 0.0f);
}

__global__ void fbias_k(const float* __restrict__ wqb, const float* __restrict__ rkvb,
                        float* __restrict__ fb) {
  int i = blockIdx.x * 256 + threadIdx.x;
  if (i >= L_ * 2304) return;
  int l = i / 2304, c = i - l * 2304;
  fb[i] = (c < 768) ? wqb[l * 768 + c] : rkvb[l * 1536 + (c - 768)];
}

// --------------------------------------------------------------- misc ----
__global__ void init_scene_k(const float* __restrict__ tok, float* __restrict__ sf,
                             unsigned short* __restrict__ sb, int total) {
  int i = blockIdx.x * 256 + threadIdx.x;
  if (i < total) {
    float v = tok[i % (S_ * D_)];
    sf[i] = v; sb[i] = f2bf(v);
  }
}

__global__ void rope_scene_k(float* __restrict__ c, float* __restrict__ s) {
  int idx = blockIdx.x * 256 + threadIdx.x;
  if (idx >= S_ * 32) return;
  int t = idx >> 5, m = idx & 31;
  int i = t >> 4, j = t & 15;
  float xx = -1.0f + 2.0f * j / 15.0f;
  float yy = -1.0f + 2.0f * i / 15.0f;
  float coord = (m < 16) ? xx : yy;
  float per = powf(100.0f, (float)(m & 15) / 16.0f);
  float ang = coord / per;
  c[idx] = cosf(ang); s[idx] = sinf(ang);
}

__global__ void rope_local_k(float* __restrict__ c, float* __restrict__ s,
                             const float* __restrict__ ctr, const float* __restrict__ scl) {
  int idx = blockIdx.x * 256 + threadIdx.x;
  if (idx >= B_ * N_ * 32) return;
  int b = idx / (N_ * 32);
  int r = idx - b * (N_ * 32);
  int pch = r >> 5, m = r & 31;
  int py = pch / 7, px = pch - py * 7;
  float cx = ctr[b * 2], cy = ctr[b * 2 + 1], sc = scl[b];
  float gx = cx + sc * ((px - 3.0f) / 3.0f);
  float gy = cy + sc * ((py - 3.0f) / 3.0f);
  float coord = (m < 16) ? gx : gy;
  float per = powf(100.0f, (float)(m & 15) / 16.0f);
  float ang = coord / per;
  c[idx] = cosf(ang); s[idx] = sinf(ang);
}

__global__ void im2col_k(unsigned short* __restrict__ xb, const float* __restrict__ img,
                         const float* __restrict__ ctr, const float* __restrict__ scl) {
  int idx = blockIdx.x * 256 + threadIdx.x;
  if (idx >= 784 * 768) return;
  int row = idx / 768, col = idx - row * 768;
  float val = 0.0f;
  if (col < 588) {
    int b = row / 49, pch = row - b * 49;
    int c = col / 196, rr = col - c * 196;
    int i = rr / 14, j = rr - i * 14;
    int py = pch / 7, px = pch - py * 7;
    int gyi = py * 14 + i, gxi = px * 14 + j;
    float cx = ctr[b * 2], cy = ctr[b * 2 + 1], sc = scl[b];
    float gy = cy + sc * (-1.0f + 2.0f * gyi / 97.0f);
    float gx = cx + sc * (-1.0f + 2.0f * gxi / 97.0f);
    float pyi = (gy + 1.0f) * 0.5f * 223.0f;
    float pxi = (gx + 1.0f) * 0.5f * 223.0f;
    float y0f = fminf(fmaxf(floorf(pyi), 0.0f), 222.0f);
    float x0f = fminf(fmaxf(floorf(pxi), 0.0f), 222.0f);
    int y0 = (int)y0f, x0 = (int)x0f;
    float wy = fminf(fmaxf(pyi - y0f, 0.0f), 1.0f);
    float wx = fminf(fmaxf(pxi - x0f, 0.0f), 1.0f);
    const float* base = img + (size_t)(b * 3 + c) * 224 * 224;
    float v00 = base[y0 * 224 + x0],       v01 = base[y0 * 224 + x0 + 1];
    float v10 = base[(y0 + 1) * 224 + x0], v11 = base[(y0 + 1) * 224 + x0 + 1];
    val = (v00 * (1.0f - wy) + v10 * wy) * (1.0f - wx) + (v01 * (1.0f - wy) + v11 * wy) * wx;
  }
  xb[idx] = f2bf(val);
}

// -------------------------------------------------------------- launch ----
extern "C" void kernel_launch(void* const* d_in, const int* in_sizes, int n_in,
                              void* d_out, int out_size, void* d_ws, size_t ws_size,
                              hipStream_t stream) {
  const float* images    = (const float*)d_in[0];
  const float* centers   = (const float*)d_in[1];
  const float* scales    = (const float*)d_in[2];
  const float* patch_w   = (const float*)d_in[3];
  const float* patch_b   = (const float*)d_in[4];
  const float* scene_tok = (const float*)d_in[5];
  const float* ln1_w = (const float*)d_in[6];
  const float* ln1_b = (const float*)d_in[7];
  const float* ln2_w = (const float*)d_in[8];
  const float* ln2_b = (const float*)d_in[9];
  const float* qkv_w = (const float*)d_in[10];
  const float* qkv_b = (const float*)d_in[11];
  const float* ao_w  = (const float*)d_in[12];
  const float* ao_b  = (const float*)d_in[13];
  const float* m1_w  = (const float*)d_in[14];
  const float* m1_b  = (const float*)d_in[15];
  const float* m2_w  = (const float*)d_in[16];
  const float* m2_b  = (const float*)d_in[17];
  const float* rq_w  = (const float*)d_in[18];
  const float* rq_b  = (const float*)d_in[19];
  const float* rkv_w = (const float*)d_in[20];
  const float* rkv_b = (const float*)d_in[21];
  const float* ro_w  = (const float*)d_in[22];
  const float* ro_b  = (const float*)d_in[23];
  const float* rgate = (const float*)d_in[24];
  const float* wq_w  = (const float*)d_in[25];
  const float* wq_b  = (const float*)d_in[26];
  const float* wkv_w = (const float*)d_in[27];
  const float* wkv_b = (const float*)d_in[28];
  const float* wo_w  = (const float*)d_in[29];
  const float* wo_b  = (const float*)d_in[30];
  const float* wgate = (const float*)d_in[31];

  float* scene_f = (float*)d_out;

  char* p = (char*)d_ws;
  auto alloc = [&](size_t bytes) { char* r = p; p += (bytes + 255) & ~(size_t)255; return (void*)r; };
  unsigned short* scene_bf = (unsigned short*)alloc((size_t)4096 * 768 * 2);
  float*          local_f  = (float*)alloc((size_t)784 * 768 * 4);
  unsigned short* local_bf = (unsigned short*)alloc((size_t)832 * 768 * 2);
  float*          q_r      = (float*)alloc((size_t)784 * 768 * 4);
  float*          qrkv_f   = (float*)alloc((size_t)4096 * 2304 * 4);
  float*          kv_buf   = (float*)alloc((size_t)784 * 2304 * 4);
  unsigned short* ln_bf    = (unsigned short*)alloc((size_t)832 * 768 * 2);
  unsigned short* act_bf   = (unsigned short*)alloc((size_t)4096 * 768 * 2);
  unsigned short* x_bf     = (unsigned short*)alloc((size_t)832 * 768 * 2);
  float* sc_cos = (float*)alloc((size_t)S_ * 32 * 4);
  float* sc_sin = (float*)alloc((size_t)S_ * 32 * 4);
  float* l_cos  = (float*)alloc((size_t)B_ * N_ * 32 * 4);
  float* l_sin  = (float*)alloc((size_t)B_ * N_ * 32 * 4);
  unsigned short* patch_wbf = (unsigned short*)alloc((size_t)768 * 768 * 2);
  float*          fb        = (float*)alloc((size_t)L_ * 2304 * 4);

  // segments: 0 rq, 1 wq (fused lo), 2 rkv (fused hi), 3 ro, 4 qkv,
  //           5 ao, 6 m1, 7 m2, 8 wkv, 9 wo
  // dest regions: 0 rq, 1 [wq|rkv], 2 ro, 3 qkv, 4 ao, 5 m1, 6 m2, 7 wkv, 8 wo
  static const unsigned int LSRC[10] = {589824, 589824, 1179648, 589824, 1769472,
                                        589824, 2359296, 2359296, 1179648, 589824};
  static const unsigned int LSTR[10] = {589824, 1769472, 1769472, 589824, 1769472,
                                        589824, 2359296, 2359296, 1179648, 589824};
  static const unsigned int DOFF[10] = {0, 0, 589824, 0, 0, 0, 0, 0, 0, 0};
  const float* WSRC[10] = {rq_w, wq_w, rkv_w, ro_w, qkv_w, ao_w, m1_w, m2_w, wkv_w, wo_w};
  // per-REGION per-layer element counts (fused counted once)
  static const size_t REGSZ[9] = {589824, 1769472, 589824, 1769472, 589824,
                                  2359296, 2359296, 1179648, 589824};
  size_t regBase[9];
  size_t allElemsPerLayer = 0;
  for (int i = 0; i < 9; ++i) { regBase[i] = allElemsPerLayer * L_; allElemsPerLayer += REGSZ[i]; }
  // NOTE: regBase built from REGION sizes (round-3 bug: was built from the
  // segment table whose placeholder-0 made qkv overlap ro, ao overlap qkv,
  // m2 overlap m1).
  {
    size_t cur = 0;
    for (int i = 0; i < 9; ++i) { regBase[i] = cur; cur += REGSZ[i] * L_; }
  }
  const size_t allElems = allElemsPerLayer * L_;
  size_t usedBytes = (size_t)(p - (char*)d_ws);
  bool preconv = ws_size >= usedBytes + allElems * 2 + 4096;
  unsigned short* wbf = (unsigned short*)alloc((preconv ? allElems : allElemsPerLayer) * 2);

  enum { T128, T128x64, T64 };
  auto G = [&](int tile, const unsigned short* A, int lda, const unsigned short* Wp, int ldw,
               const float* bias, float* Cf, unsigned short* Cb, int ldc,
               const float* res, const float* gt, int M, int N, int K, int epi) {
    if (tile == T128)
      gemm_v3<128, 128, 64><<<dim3(M / 128, N / 128), 256, 0, stream>>>(
          A, lda, Wp, ldw, bias, Cf, Cb, ldc, res, gt, M, N, K, epi);
    else if (tile == T128x64)
      gemm_v3<128, 64, 64><<<dim3(M / 128, N / 64), 256, 0, stream>>>(
          A, lda, Wp, ldw, bias, Cf, Cb, ldc, res, gt, M, N, K, epi);
    else
      gemm_v3<64, 64, 256><<<dim3((M + 63) / 64, N / 64), 256, 0, stream>>>(
          A, lda, Wp, ldw, bias, Cf, Cb, ldc, res, gt, M, N, K, epi);
  };

  {
    int total = B_ * S_ * D_;
    init_scene_k<<<(total + 255) / 256, 256, 0, stream>>>(scene_tok, scene_f, scene_bf, total);
    rope_scene_k<<<(S_ * 32 + 255) / 256, 256, 0, stream>>>(sc_cos, sc_sin);
    cvt_patch_k<<<(768 * 768 + 255) / 256, 256, 0, stream>>>(patch_w, patch_wbf);
    fbias_k<<<(L_ * 2304 + 255) / 256, 256, 0, stream>>>(wq_b, rkv_b, fb);
    if (preconv) {
      CvtA cv;
      int blk = 0;
      for (int i = 0; i < 10; ++i) {
        int reg = i >= 2 ? i - 1 : i;   // seg 1 and 2 share region 1
        cv.s[i] = WSRC[i];
        cv.d[i] = wbf + regBase[reg] + DOFF[i];
        cv.lsrc[i] = LSRC[i];
        cv.lstride[i] = LSTR[i];
        blk += (int)((size_t)LSRC[i] * L_ / 2048);
        cv.blkEnd[i] = blk;
      }
      cvt_multi_k<<<blk, 256, 0, stream>>>(cv);
    }
  }

  for (int vp = 0; vp < V_; ++vp) {
    const float* ctr = centers + (size_t)vp * B_ * 2;
    const float* scl = scales + (size_t)vp * B_;
    rope_local_k<<<(B_ * N_ * 32 + 255) / 256, 256, 0, stream>>>(l_cos, l_sin, ctr, scl);
    im2col_k<<<(784 * 768 + 255) / 256, 256, 0, stream>>>(x_bf, images, ctr, scl);
    G(T64, x_bf, 768, patch_wbf, 768, patch_b, local_f, local_bf, 768,
      nullptr, nullptr, 784, 768, 768, 0);

    for (int l = 0; l < L_; ++l) {
      const unsigned short* wL[10];
      if (preconv) {
        for (int i = 0; i < 10; ++i) {
          int reg = i >= 2 ? i - 1 : i;
          wL[i] = wbf + regBase[reg] + (size_t)l * LSTR[i] + DOFF[i];
        }
      } else {
        CvtA cv;
        int blk = 0;
        size_t cur = 0;
        size_t rb[9];
        for (int i = 0; i < 10; ++i) {
          int reg = i >= 2 ? i - 1 : i;
          if (i != 2) { rb[reg] = cur; cur += REGSZ[reg]; }
          cv.s[i] = WSRC[i] + (size_t)l * LSRC[i];
          cv.d[i] = wbf + rb[reg] + DOFF[i];
          cv.lsrc[i] = LSRC[i];
          cv.lstride[i] = LSTR[i];
          blk += (int)(LSRC[i] / 2048);
          cv.blkEnd[i] = blk;
          wL[i] = (unsigned short*)cv.d[i];
        }
        cvt_multi_k<<<blk, 256, 0, stream>>>(cv);
      }
      const unsigned short *w_rq = wL[0], *w_qrkv = wL[1], *w_ro = wL[3], *w_qkv = wL[4],
                           *w_ao = wL[5], *w_m1 = wL[6], *w_m2 = wL[7], *w_wkv = wL[8],
                           *w_wo = wL[9];

      // ---- fused wq+rkv on scene; rq on local ----
      G(T128, scene_bf, 768, w_qrkv, 768, fb + (size_t)l * 2304,
        qrkv_f, nullptr, 2304, nullptr, nullptr, 4096, 2304, 768, 0);
      G(T64, local_bf, 768, w_rq, 768, rq_b + l * 768,
        q_r, nullptr, 768, nullptr, nullptr, 784, 768, 768, 0);
      // ---- read cross: local queries scene KV ----
      attn_k<<<dim3(B_ * NH_, 2), 256, 0, stream>>>(q_r, 768, 0, 49,
          qrkv_f, 2304, 768, 1536, 256, l_cos, l_sin, N_ * 32, sc_cos, sc_sin, 0, act_bf);
      G(T64, act_bf, 768, w_ro, 768, ro_b + l * 768,
        local_f, local_bf, 768, local_f, rgate + l * 768, 784, 768, 768, 2);
      // ---- self attention ----
      ln_kernel<<<784, 256, 0, stream>>>(local_f, ln1_w + l * 768, ln1_b + l * 768, ln_bf);
      G(T64, ln_bf, 768, w_qkv, 768, qkv_b + (size_t)l * 2304,
        kv_buf, nullptr, 2304, nullptr, nullptr, 784, 2304, 768, 0);
      attn_k<<<dim3(B_ * NH_, 2), 256, 0, stream>>>(kv_buf, 2304, 0, 49,
          kv_buf, 2304, 768, 1536, 49, l_cos, l_sin, N_ * 32, l_cos, l_sin, N_ * 32, act_bf);
      G(T64, act_bf, 768, w_ao, 768, ao_b + l * 768,
        local_f, local_bf, 768, local_f, nullptr, 784, 768, 768, 2);
      // ---- MLP ----
      ln_kernel<<<784, 256, 0, stream>>>(local_f, ln2_w + l * 768, ln2_b + l * 768, ln_bf);
      G(T64, ln_bf, 768, w_m1, 768, m1_b + (size_t)l * 3072,
        nullptr, act_bf, 3072, nullptr, nullptr, 784, 3072, 768, 1);
      G(T64, act_bf, 3072, w_m2, 3072, m2_b + l * 768,
        local_f, local_bf, 768, local_f, nullptr, 784, 768, 3072, 2);
      // ---- write cross: scene queries local KV ----
      G(T64, local_bf, 768, w_wkv, 768, wkv_b + (size_t)l * 1536,
        kv_buf, nullptr, 1536, nullptr, nullptr, 784, 1536, 768, 0);
      attn_k<<<dim3(B_ * NH_, 4), 256, 0, stream>>>(qrkv_f, 2304, 0, 256,
          kv_buf, 1536, 0, 768, 49, sc_cos, sc_sin, 0, l_cos, l_sin, N_ * 32, act_bf);
      G(T128x64, act_bf, 768, w_wo, 768, wo_b + l * 768,
        scene_f, scene_bf, 768, scene_f, wgate + l * 768, 4096, 768, 768, 2);
    }
  }
}

// Round 5
// 8691.128 us; speedup vs baseline: 3.2776x; 1.2346x over previous
//
#include <hip/hip_runtime.h>

#define B_ 16
#define V_ 2
#define D_ 768
#define NH_ 12
#define L_ 12
#define DH_ 64
#define N_ 49
#define S_ 256

__device__ __forceinline__ unsigned short f2bf(float f) {
  unsigned int u = __builtin_bit_cast(unsigned int, f);
  u += 0x7fffu + ((u >> 16) & 1u);
  return (unsigned short)(u >> 16);
}
__device__ __forceinline__ float bf2f(unsigned short h) {
  unsigned int u = ((unsigned int)h) << 16;
  return __builtin_bit_cast(float, u);
}
__device__ __forceinline__ float bflo(unsigned int w) {
  return __builtin_bit_cast(float, w << 16);
}
__device__ __forceinline__ float bfhi(unsigned int w) {
  return __builtin_bit_cast(float, w & 0xffff0000u);
}
__device__ __forceinline__ unsigned int packbf2(float a, float b) {
  return (unsigned int)f2bf(a) | ((unsigned int)f2bf(b) << 16);
}

using bf16x8 = __attribute__((ext_vector_type(8))) __bf16;
using u16x8  = __attribute__((ext_vector_type(8))) unsigned short;
using f32x4  = __attribute__((ext_vector_type(4))) float;

__device__ __forceinline__ void g2l16(const unsigned short* g, unsigned short* l) {
  __builtin_amdgcn_global_load_lds(
      (const __attribute__((address_space(1))) unsigned int*)g,
      (__attribute__((address_space(3))) unsigned int*)l, 16, 0, 0);
}

// ---------------------------------------------------------------- GEMM ----
// C(MxN) = A(MxK bf16 rm) @ W(NxK bf16 rm)^T + bias. 2-stage dbuf with
// COUNTED vmcnt (T4): next tile's loads stay in flight across the barrier.
// XOR-swizzled LDS (slot ^= row&7, 16B slots). epi: 0=none,1=gelu,2=res+gate.
template <int BM, int BN, int BK>
__global__ __launch_bounds__(256) void gemm_v4(
    const unsigned short* __restrict__ A, int lda,
    const unsigned short* __restrict__ W, int ldw,
    const float* __restrict__ bias,
    float* __restrict__ Cf, unsigned short* __restrict__ Cb, int ldc,
    const float* __restrict__ res, const float* __restrict__ gate,
    int M, int N, int K, int epi)
{
  __shared__ unsigned short As[2][BM * BK];
  __shared__ unsigned short Bs[2][BN * BK];
  constexpr int FM = BM / 32, FN = BN / 32;
  constexpr int CPR = BK / 8;
  constexpr int LPS = (BM + BN) * BK / 2048;   // per-thread loads per stage
  const int m0 = blockIdx.x * BM, n0 = blockIdx.y * BN;
  const int tid = threadIdx.x, lane = tid & 63, wid = tid >> 6;
  const int wr = wid >> 1, wc = wid & 1;
  const int fr = lane & 15, kq8 = lane >> 4;

  f32x4 acc[FM][FN];
#pragma unroll
  for (int mi = 0; mi < FM; ++mi)
#pragma unroll
    for (int ni = 0; ni < FN; ++ni) acc[mi][ni] = f32x4{0.f, 0.f, 0.f, 0.f};

  auto stage = [&](int buf, int k0) {
    const unsigned short* Ab = A + (size_t)m0 * lda + k0;
    const unsigned short* Bb = W + (size_t)n0 * ldw + k0;
#pragma unroll
    for (int ra = 0; ra < BM * BK / 2048; ++ra) {
      int c = ra * 256 + tid;
      int row = c / CPR, slot = c % CPR;
      int gslot = slot ^ (row & 7);
      g2l16(Ab + (size_t)row * lda + gslot * 8, &As[buf][c * 8]);
    }
#pragma unroll
    for (int rb = 0; rb < BN * BK / 2048; ++rb) {
      int c = rb * 256 + tid;
      int row = c / CPR, slot = c % CPR;
      int gslot = slot ^ (row & 7);
      g2l16(Bb + (size_t)row * ldw + gslot * 8, &Bs[buf][c * 8]);
    }
  };

  const int nt = K / BK;
  stage(0, 0);
  int cur = 0;
  for (int t = 0; t < nt; ++t) {
    if (t + 1 < nt) {
      stage(cur ^ 1, (t + 1) * BK);
      asm volatile("s_waitcnt vmcnt(%0)" :: "i"(LPS) : "memory");
    } else {
      asm volatile("s_waitcnt vmcnt(0)" ::: "memory");
    }
    __builtin_amdgcn_s_barrier();
#pragma unroll
    for (int ks = 0; ks < BK / 32; ++ks) {
      bf16x8 av[FM], bv[FN];
#pragma unroll
      for (int mi = 0; mi < FM; ++mi) {
        int row = wr * (BM / 2) + mi * 16 + fr;
        int idx = row * BK + (((ks * 4 + kq8) ^ (row & 7)) << 3);
        av[mi] = __builtin_bit_cast(bf16x8, *(const u16x8*)&As[cur][idx]);
      }
#pragma unroll
      for (int ni = 0; ni < FN; ++ni) {
        int row = wc * (BN / 2) + ni * 16 + fr;
        int idx = row * BK + (((ks * 4 + kq8) ^ (row & 7)) << 3);
        bv[ni] = __builtin_bit_cast(bf16x8, *(const u16x8*)&Bs[cur][idx]);
      }
#pragma unroll
      for (int mi = 0; mi < FM; ++mi)
#pragma unroll
        for (int ni = 0; ni < FN; ++ni)
          acc[mi][ni] = __builtin_amdgcn_mfma_f32_16x16x32_bf16(av[mi], bv[ni], acc[mi][ni], 0, 0, 0);
    }
    __builtin_amdgcn_s_barrier();
    cur ^= 1;
  }

  const int er = (lane >> 4) * 4, ec = lane & 15;
#pragma unroll
  for (int mi = 0; mi < FM; ++mi)
#pragma unroll
    for (int ni = 0; ni < FN; ++ni) {
      int gc = n0 + wc * (BN / 2) + ni * 16 + ec;
      float bi = bias ? bias[gc] : 0.0f;
      float gg = gate ? gate[gc] : 1.0f;
#pragma unroll
      for (int i = 0; i < 4; ++i) {
        int gr = m0 + wr * (BM / 2) + mi * 16 + er + i;
        if (gr < M) {
          float v = acc[mi][ni][i] + bi;
          if (epi == 1) {
            v = v / (1.0f + __expf(-1.59576912f * (v + 0.044715f * v * v * v)));
          } else if (epi == 2) {
            v = res[(size_t)gr * ldc + gc] + gg * v;
          }
          if (Cf) Cf[(size_t)gr * ldc + gc] = v;
          if (Cb) Cb[(size_t)gr * ldc + gc] = f2bf(v);
        }
      }
    }
}

// ----------------------------------------------------------- attention ----
// All-bf16 inputs. K bf16 chunk-swizzled [t][64]; V bf16 TRANSPOSED [d][S_]
// chunk-swizzled so PV reads u16x8 per lane. p fp32 broadcast. 1/8 in K.
__global__ __launch_bounds__(256) void attn_k(
    const unsigned short* __restrict__ Q, int ldq, int qoff, int Lq,
    const unsigned short* __restrict__ KV, int ldkv, int koff, int voff, int Lk,
    const float* __restrict__ cq, const float* __restrict__ sq, int rbq,
    const float* __restrict__ ck, const float* __restrict__ sk, int rbk,
    unsigned short* __restrict__ Out)
{
  __shared__ unsigned short Kb[S_ * DH_];   // 32 KB
  __shared__ unsigned short Vt[DH_ * S_];   // 32 KB, transposed
  __shared__ float qsh[4][DH_];
  __shared__ float pb[4][S_];
  const int b = blockIdx.x / NH_, h = blockIdx.x - b * NH_;
  const int tid = threadIdx.x, lane = tid & 63, wid = tid >> 6;
  const int NC = (Lk + 7) >> 3;
  const int Tpad = NC << 3;

  for (int idx = tid; idx < Tpad * 32; idx += 256) {
    int t = idx >> 5, m = idx & 31;
    int d = 2 * m;
    int vs0 = d * S_ + (((t >> 3) ^ (d & 7)) << 3) + (t & 7);
    int vs1 = (d + 1) * S_ + (((t >> 3) ^ ((d + 1) & 7)) << 3) + (t & 7);
    if (t < Lk) {
      size_t rowb = ((size_t)b * Lk + t) * ldkv;
      unsigned int kw = *(const unsigned int*)(KV + rowb + koff + h * DH_ + d);
      unsigned int vw = *(const unsigned int*)(KV + rowb + voff + h * DH_ + d);
      float k1 = bf2f((unsigned short)(kw & 0xffff)), k2 = bf2f((unsigned short)(kw >> 16));
      size_t ri = (size_t)b * rbk + (size_t)t * 32 + m;
      float c = ck[ri], s = sk[ri];
      unsigned int kr = packbf2((k1 * c - k2 * s) * 0.125f, (k1 * s + k2 * c) * 0.125f);
      int scm = (m >> 2) ^ (t & 7);
      *(unsigned int*)&Kb[(t << 6) + (scm << 3) + ((m & 3) << 1)] = kr;
      Vt[vs0] = (unsigned short)(vw & 0xffff);
      Vt[vs1] = (unsigned short)(vw >> 16);
    } else {
      Vt[vs0] = 0;
      Vt[vs1] = 0;
    }
  }
  __syncthreads();

  const int nt = (Lk + 63) >> 6;
  const int nspl = gridDim.y;
  const int rows = (Lq + nspl - 1) / nspl;
  const int r0 = blockIdx.y * rows;
  const int r1 = (Lq < r0 + rows) ? Lq : (r0 + rows);

  for (int r = r0 + wid; r < r1; r += 4) {
    float x = bf2f(Q[((size_t)b * Lq + r) * ldq + qoff + h * DH_ + lane]);
    float px = __shfl_xor(x, 1);
    size_t ri = (size_t)b * rbq + (size_t)r * 32 + (lane >> 1);
    float c = cq[ri], s = sq[ri];
    float qr = (lane & 1) ? (px * s + x * c) : (x * c - px * s);
    qsh[wid][lane] = qr;
    __asm__ volatile("s_waitcnt lgkmcnt(0)" ::: "memory");
    f32x4 qv[16];
#pragma unroll
    for (int cc = 0; cc < 16; ++cc) qv[cc] = *(const f32x4*)&qsh[wid][cc * 4];

    float sc0 = -1e30f, sc1 = -1e30f, sc2 = -1e30f, sc3 = -1e30f;
#pragma unroll
    for (int j = 0; j < 4; ++j) {
      if (j < nt) {
        int t = lane + (j << 6);
        if (t < Lk) {
          const unsigned short* kp = &Kb[t << 6];
          int sw = t & 7;
          float a0 = 0.f, a1 = 0.f, a2 = 0.f, a3 = 0.f;
#pragma unroll
          for (int cc = 0; cc < 8; ++cc) {
            u16x8 kk = *(const u16x8*)(kp + ((cc ^ sw) << 3));
            const unsigned int* kwp = (const unsigned int*)&kk;
            f32x4 qa = qv[2 * cc], qb = qv[2 * cc + 1];
            a0 += qa.x * bflo(kwp[0]); a1 += qa.y * bfhi(kwp[0]);
            a2 += qa.z * bflo(kwp[1]); a3 += qa.w * bfhi(kwp[1]);
            a0 += qb.x * bflo(kwp[2]); a1 += qb.y * bfhi(kwp[2]);
            a2 += qb.z * bflo(kwp[3]); a3 += qb.w * bfhi(kwp[3]);
          }
          float v = (a0 + a1) + (a2 + a3);
          if (j == 0) sc0 = v; else if (j == 1) sc1 = v; else if (j == 2) sc2 = v; else sc3 = v;
        }
      }
    }
    float mx = fmaxf(fmaxf(sc0, sc1), fmaxf(sc2, sc3));
    for (int o = 32; o; o >>= 1) mx = fmaxf(mx, __shfl_xor(mx, o));
    float sum;
    { float e = __expf(sc0 - mx); pb[wid][lane] = e; sum = e; }
    if (nt > 1) { float e = __expf(sc1 - mx); pb[wid][lane + 64]  = e; sum += e; }
    if (nt > 2) { float e = __expf(sc2 - mx); pb[wid][lane + 128] = e; sum += e; }
    if (nt > 3) { float e = __expf(sc3 - mx); pb[wid][lane + 192] = e; sum += e; }
    for (int o = 32; o; o >>= 1) sum += __shfl_xor(sum, o);
    float inv = 1.0f / sum;
    __asm__ volatile("s_waitcnt lgkmcnt(0)" ::: "memory");

    float oa = 0.f, ob = 0.f, oc = 0.f, od4 = 0.f;
    const unsigned short* vp = &Vt[lane * S_];
    const int sw2 = lane & 7;
    for (int ct = 0; ct < NC; ++ct) {
      u16x8 vv = *(const u16x8*)(vp + ((ct ^ sw2) << 3));
      f32x4 p0 = *(const f32x4*)&pb[wid][ct * 8];
      f32x4 p1 = *(const f32x4*)&pb[wid][ct * 8 + 4];
      const unsigned int* vw = (const unsigned int*)&vv;
      oa  += p0.x * bflo(vw[0]); ob  += p0.y * bfhi(vw[0]);
      oc  += p0.z * bflo(vw[1]); od4 += p0.w * bfhi(vw[1]);
      oa  += p1.x * bflo(vw[2]); ob  += p1.y * bfhi(vw[2]);
      oc  += p1.z * bflo(vw[3]); od4 += p1.w * bfhi(vw[3]);
    }
    float od = ((oa + ob) + (oc + od4)) * inv;
    Out[((size_t)b * Lq + r) * D_ + h * DH_ + lane] = f2bf(od);
  }
}

// ----------------------------------------------------------- layernorm ----
__global__ __launch_bounds__(256) void ln_kernel(
    const float* __restrict__ X, const float* __restrict__ w,
    const float* __restrict__ bsh, unsigned short* __restrict__ Out)
{
  const int row = blockIdx.x, tid = threadIdx.x;
  const float* x = X + (size_t)row * D_;
  float v0 = x[tid], v1 = x[tid + 256], v2 = x[tid + 512];
  __shared__ float red[4];
  float s = v0 + v1 + v2;
  for (int o = 32; o; o >>= 1) s += __shfl_xor(s, o);
  if ((tid & 63) == 0) red[tid >> 6] = s;
  __syncthreads();
  float mean = (red[0] + red[1] + red[2] + red[3]) * (1.0f / 768.0f);
  float d0 = v0 - mean, d1 = v1 - mean, d2 = v2 - mean;
  float q = d0 * d0 + d1 * d1 + d2 * d2;
  __syncthreads();
  for (int o = 32; o; o >>= 1) q += __shfl_xor(q, o);
  if ((tid & 63) == 0) red[tid >> 6] = q;
  __syncthreads();
  float var = (red[0] + red[1] + red[2] + red[3]) * (1.0f / 768.0f);
  float rstd = rsqrtf(var + 1e-6f);
  Out[(size_t)row * D_ + tid]       = f2bf(d0 * rstd * w[tid]       + bsh[tid]);
  Out[(size_t)row * D_ + tid + 256] = f2bf(d1 * rstd * w[tid + 256] + bsh[tid + 256]);
  Out[(size_t)row * D_ + tid + 512] = f2bf(d2 * rstd * w[tid + 512] + bsh[tid + 512]);
}

// ------------------------------------------------------ weight convert ----
struct CvtA {
  const float* s[10];
  unsigned short* d[10];
  unsigned int lsrc[10];
  unsigned int lstride[10];
  int blkEnd[10];
};
__global__ __launch_bounds__(256) void cvt_multi_k(CvtA c) {
  int bid = blockIdx.x;
  int seg = 0;
#pragma unroll
  for (int i = 0; i < 9; ++i) seg += (bid >= c.blkEnd[i]) ? 1 : 0;
  unsigned int e = (unsigned int)(bid - (seg ? c.blkEnd[seg - 1] : 0)) * 2048u
                   + (unsigned int)threadIdx.x * 8u;
  unsigned int l = e / c.lsrc[seg], r = e - l * c.lsrc[seg];
  const float* s = c.s[seg] + e;
  unsigned short* d = c.d[seg] + (size_t)l * c.lstride[seg] + r;
  f32x4 a = *(const f32x4*)s, b2 = *(const f32x4*)(s + 4);
  u16x8 o;
  o[0] = f2bf(a.x); o[1] = f2bf(a.y); o[2] = f2bf(a.z); o[3] = f2bf(a.w);
  o[4] = f2bf(b2.x); o[5] = f2bf(b2.y); o[6] = f2bf(b2.z); o[7] = f2bf(b2.w);
  *(u16x8*)d = o;
}

__global__ void cvt_patch_k(const float* __restrict__ s, unsigned short* __restrict__ d) {
  int i = blockIdx.x * 256 + threadIdx.x;
  if (i >= 768 * 768) return;
  int r = i / 768, col = i - r * 768;
  d[i] = f2bf(col < 588 ? s[r * 588 + col] : 0.0f);
}

__global__ void fbias_k(const float* __restrict__ wqb, const float* __restrict__ rkvb,
                        float* __restrict__ fb) {
  int i = blockIdx.x * 256 + threadIdx.x;
  if (i >= L_ * 2304) return;
  int l = i / 2304, c = i - l * 2304;
  fb[i] = (c < 768) ? wqb[l * 768 + c] : rkvb[l * 1536 + (c - 768)];
}

// --------------------------------------------------------------- misc ----
__global__ void init_scene_k(const float* __restrict__ tok, float* __restrict__ sf,
                             unsigned short* __restrict__ sb, int total) {
  int i = blockIdx.x * 256 + threadIdx.x;
  if (i < total) {
    float v = tok[i % (S_ * D_)];
    sf[i] = v; sb[i] = f2bf(v);
  }
}

__global__ void rope_scene_k(float* __restrict__ c, float* __restrict__ s) {
  int idx = blockIdx.x * 256 + threadIdx.x;
  if (idx >= S_ * 32) return;
  int t = idx >> 5, m = idx & 31;
  int i = t >> 4, j = t & 15;
  float xx = -1.0f + 2.0f * j / 15.0f;
  float yy = -1.0f + 2.0f * i / 15.0f;
  float coord = (m < 16) ? xx : yy;
  float per = powf(100.0f, (float)(m & 15) / 16.0f);
  float ang = coord / per;
  c[idx] = cosf(ang); s[idx] = sinf(ang);
}

__global__ void rope_local_k(float* __restrict__ c, float* __restrict__ s,
                             const float* __restrict__ ctr, const float* __restrict__ scl) {
  int idx = blockIdx.x * 256 + threadIdx.x;
  if (idx >= B_ * N_ * 32) return;
  int b = idx / (N_ * 32);
  int r = idx - b * (N_ * 32);
  int pch = r >> 5, m = r & 31;
  int py = pch / 7, px = pch - py * 7;
  float cx = ctr[b * 2], cy = ctr[b * 2 + 1], sc = scl[b];
  float gx = cx + sc * ((px - 3.0f) / 3.0f);
  float gy = cy + sc * ((py - 3.0f) / 3.0f);
  float coord = (m < 16) ? gx : gy;
  float per = powf(100.0f, (float)(m & 15) / 16.0f);
  float ang = coord / per;
  c[idx] = cosf(ang); s[idx] = sinf(ang);
}

__global__ void im2col_k(unsigned short* __restrict__ xb, const float* __restrict__ img,
                         const float* __restrict__ ctr, const float* __restrict__ scl) {
  int idx = blockIdx.x * 256 + threadIdx.x;
  if (idx >= 784 * 768) return;
  int row = idx / 768, col = idx - row * 768;
  float val = 0.0f;
  if (col < 588) {
    int b = row / 49, pch = row - b * 49;
    int c = col / 196, rr = col - c * 196;
    int i = rr / 14, j = rr - i * 14;
    int py = pch / 7, px = pch - py * 7;
    int gyi = py * 14 + i, gxi = px * 14 + j;
    float cx = ctr[b * 2], cy = ctr[b * 2 + 1], sc = scl[b];
    float gy = cy + sc * (-1.0f + 2.0f * gyi / 97.0f);
    float gx = cx + sc * (-1.0f + 2.0f * gxi / 97.0f);
    float pyi = (gy + 1.0f) * 0.5f * 223.0f;
    float pxi = (gx + 1.0f) * 0.5f * 223.0f;
    float y0f = fminf(fmaxf(floorf(pyi), 0.0f), 222.0f);
    float x0f = fminf(fmaxf(floorf(pxi), 0.0f), 222.0f);
    int y0 = (int)y0f, x0 = (int)x0f;
    float wy = fminf(fmaxf(pyi - y0f, 0.0f), 1.0f);
    float wx = fminf(fmaxf(pxi - x0f, 0.0f), 1.0f);
    const float* base = img + (size_t)(b * 3 + c) * 224 * 224;
    float v00 = base[y0 * 224 + x0],       v01 = base[y0 * 224 + x0 + 1];
    float v10 = base[(y0 + 1) * 224 + x0], v11 = base[(y0 + 1) * 224 + x0 + 1];
    val = (v00 * (1.0f - wy) + v10 * wy) * (1.0f - wx) + (v01 * (1.0f - wy) + v11 * wy) * wx;
  }
  xb[idx] = f2bf(val);
}

// -------------------------------------------------------------- launch ----
extern "C" void kernel_launch(void* const* d_in, const int* in_sizes, int n_in,
                              void* d_out, int out_size, void* d_ws, size_t ws_size,
                              hipStream_t stream) {
  const float* images    = (const float*)d_in[0];
  const float* centers   = (const float*)d_in[1];
  const float* scales    = (const float*)d_in[2];
  const float* patch_w   = (const float*)d_in[3];
  const float* patch_b   = (const float*)d_in[4];
  const float* scene_tok = (const float*)d_in[5];
  const float* ln1_w = (const float*)d_in[6];
  const float* ln1_b = (const float*)d_in[7];
  const float* ln2_w = (const float*)d_in[8];
  const float* ln2_b = (const float*)d_in[9];
  const float* qkv_w = (const float*)d_in[10];
  const float* qkv_b = (const float*)d_in[11];
  const float* ao_w  = (const float*)d_in[12];
  const float* ao_b  = (const float*)d_in[13];
  const float* m1_w  = (const float*)d_in[14];
  const float* m1_b  = (const float*)d_in[15];
  const float* m2_w  = (const float*)d_in[16];
  const float* m2_b  = (const float*)d_in[17];
  const float* rq_w  = (const float*)d_in[18];
  const float* rq_b  = (const float*)d_in[19];
  const float* rkv_w = (const float*)d_in[20];
  const float* rkv_b = (const float*)d_in[21];
  const float* ro_w  = (const float*)d_in[22];
  const float* ro_b  = (const float*)d_in[23];
  const float* rgate = (const float*)d_in[24];
  const float* wq_w  = (const float*)d_in[25];
  const float* wq_b  = (const float*)d_in[26];
  const float* wkv_w = (const float*)d_in[27];
  const float* wkv_b = (const float*)d_in[28];
  const float* wo_w  = (const float*)d_in[29];
  const float* wo_b  = (const float*)d_in[30];
  const float* wgate = (const float*)d_in[31];

  float* scene_f = (float*)d_out;

  char* p = (char*)d_ws;
  auto alloc = [&](size_t bytes) { char* r = p; p += (bytes + 255) & ~(size_t)255; return (void*)r; };
  unsigned short* scene_bf = (unsigned short*)alloc((size_t)4096 * 768 * 2);
  float*          local_f  = (float*)alloc((size_t)784 * 768 * 4);
  unsigned short* local_bf = (unsigned short*)alloc((size_t)832 * 768 * 2);
  unsigned short* q_r_bf   = (unsigned short*)alloc((size_t)784 * 768 * 2);
  unsigned short* qrkv_bf  = (unsigned short*)alloc((size_t)4096 * 2304 * 2);
  unsigned short* kv_bf    = (unsigned short*)alloc((size_t)784 * 2304 * 2);
  unsigned short* ln_bf    = (unsigned short*)alloc((size_t)832 * 768 * 2);
  unsigned short* act_bf   = (unsigned short*)alloc((size_t)4096 * 768 * 2);
  unsigned short* x_bf     = (unsigned short*)alloc((size_t)832 * 768 * 2);
  float* sc_cos = (float*)alloc((size_t)S_ * 32 * 4);
  float* sc_sin = (float*)alloc((size_t)S_ * 32 * 4);
  float* l_cos  = (float*)alloc((size_t)B_ * N_ * 32 * 4);
  float* l_sin  = (float*)alloc((size_t)B_ * N_ * 32 * 4);
  unsigned short* patch_wbf = (unsigned short*)alloc((size_t)768 * 768 * 2);
  float*          fb        = (float*)alloc((size_t)L_ * 2304 * 4);

  // segments: 0 rq, 1 wq(fused lo), 2 rkv(fused hi), 3 ro, 4 qkv,
  //           5 ao, 6 m1, 7 m2, 8 wkv, 9 wo
  static const unsigned int LSRC[10] = {589824, 589824, 1179648, 589824, 1769472,
                                        589824, 2359296, 2359296, 1179648, 589824};
  static const unsigned int LSTR[10] = {589824, 1769472, 1769472, 589824, 1769472,
                                        589824, 2359296, 2359296, 1179648, 589824};
  static const unsigned int DOFF[10] = {0, 0, 589824, 0, 0, 0, 0, 0, 0, 0};
  const float* WSRC[10] = {rq_w, wq_w, rkv_w, ro_w, qkv_w, ao_w, m1_w, m2_w, wkv_w, wo_w};
  static const size_t REGSZ[9] = {589824, 1769472, 589824, 1769472, 589824,
                                  2359296, 2359296, 1179648, 589824};
  size_t regBase[9];
  size_t allElemsPerLayer = 0;
  {
    size_t cur = 0;
    for (int i = 0; i < 9; ++i) { regBase[i] = cur; cur += REGSZ[i] * L_; allElemsPerLayer += REGSZ[i]; }
  }
  const size_t allElems = allElemsPerLayer * L_;
  size_t usedBytes = (size_t)(p - (char*)d_ws);
  bool preconv = ws_size >= usedBytes + allElems * 2 + 4096;
  unsigned short* wbf = (unsigned short*)alloc((preconv ? allElems : allElemsPerLayer) * 2);

  enum { T128, T128x64, T64 };
  auto G = [&](int tile, const unsigned short* A, int lda, const unsigned short* Wp, int ldw,
               const float* bias, float* Cf, unsigned short* Cb, int ldc,
               const float* res, const float* gt, int M, int N, int K, int epi) {
    if (tile == T128)
      gemm_v4<128, 128, 64><<<dim3(M / 128, N / 128), 256, 0, stream>>>(
          A, lda, Wp, ldw, bias, Cf, Cb, ldc, res, gt, M, N, K, epi);
    else if (tile == T128x64)
      gemm_v4<128, 64, 64><<<dim3(M / 128, N / 64), 256, 0, stream>>>(
          A, lda, Wp, ldw, bias, Cf, Cb, ldc, res, gt, M, N, K, epi);
    else
      gemm_v4<64, 64, 128><<<dim3((M + 63) / 64, N / 64), 256, 0, stream>>>(
          A, lda, Wp, ldw, bias, Cf, Cb, ldc, res, gt, M, N, K, epi);
  };

  {
    int total = B_ * S_ * D_;
    init_scene_k<<<(total + 255) / 256, 256, 0, stream>>>(scene_tok, scene_f, scene_bf, total);
    rope_scene_k<<<(S_ * 32 + 255) / 256, 256, 0, stream>>>(sc_cos, sc_sin);
    cvt_patch_k<<<(768 * 768 + 255) / 256, 256, 0, stream>>>(patch_w, patch_wbf);
    fbias_k<<<(L_ * 2304 + 255) / 256, 256, 0, stream>>>(wq_b, rkv_b, fb);
    if (preconv) {
      CvtA cv;
      int blk = 0;
      for (int i = 0; i < 10; ++i) {
        int reg = i >= 2 ? i - 1 : i;
        cv.s[i] = WSRC[i];
        cv.d[i] = wbf + regBase[reg] + DOFF[i];
        cv.lsrc[i] = LSRC[i];
        cv.lstride[i] = LSTR[i];
        blk += (int)((size_t)LSRC[i] * L_ / 2048);
        cv.blkEnd[i] = blk;
      }
      cvt_multi_k<<<blk, 256, 0, stream>>>(cv);
    }
  }

  for (int vp = 0; vp < V_; ++vp) {
    const float* ctr = centers + (size_t)vp * B_ * 2;
    const float* scl = scales + (size_t)vp * B_;
    rope_local_k<<<(B_ * N_ * 32 + 255) / 256, 256, 0, stream>>>(l_cos, l_sin, ctr, scl);
    im2col_k<<<(784 * 768 + 255) / 256, 256, 0, stream>>>(x_bf, images, ctr, scl);
    G(T64, x_bf, 768, patch_wbf, 768, patch_b, local_f, local_bf, 768,
      nullptr, nullptr, 784, 768, 768, 0);

    for (int l = 0; l < L_; ++l) {
      const unsigned short* wL[10];
      if (preconv) {
        for (int i = 0; i < 10; ++i) {
          int reg = i >= 2 ? i - 1 : i;
          wL[i] = wbf + regBase[reg] + (size_t)l * LSTR[i] + DOFF[i];
        }
      } else {
        CvtA cv;
        int blk = 0;
        size_t cur = 0;
        size_t rb[9];
        for (int i = 0; i < 10; ++i) {
          int reg = i >= 2 ? i - 1 : i;
          if (i != 2) { rb[reg] = cur; cur += REGSZ[reg]; }
          cv.s[i] = WSRC[i] + (size_t)l * LSRC[i];
          cv.d[i] = wbf + rb[reg] + DOFF[i];
          cv.lsrc[i] = LSRC[i];
          cv.lstride[i] = LSTR[i];
          blk += (int)(LSRC[i] / 2048);
          cv.blkEnd[i] = blk;
          wL[i] = (unsigned short*)cv.d[i];
        }
        cvt_multi_k<<<blk, 256, 0, stream>>>(cv);
      }
      const unsigned short *w_rq = wL[0], *w_qrkv = wL[1], *w_ro = wL[3], *w_qkv = wL[4],
                           *w_ao = wL[5], *w_m1 = wL[6], *w_m2 = wL[7], *w_wkv = wL[8],
                           *w_wo = wL[9];

      // ---- fused wq+rkv on scene (bf16 out); rq on local (bf16 out) ----
      G(T128, scene_bf, 768, w_qrkv, 768, fb + (size_t)l * 2304,
        nullptr, qrkv_bf, 2304, nullptr, nullptr, 4096, 2304, 768, 0);
      G(T64, local_bf, 768, w_rq, 768, rq_b + l * 768,
        nullptr, q_r_bf, 768, nullptr, nullptr, 784, 768, 768, 0);
      // ---- read cross: local queries scene KV ----
      attn_k<<<dim3(B_ * NH_, 2), 256, 0, stream>>>(q_r_bf, 768, 0, 49,
          qrkv_bf, 2304, 768, 1536, 256, l_cos, l_sin, N_ * 32, sc_cos, sc_sin, 0, act_bf);
      G(T64, act_bf, 768, w_ro, 768, ro_b + l * 768,
        local_f, local_bf, 768, local_f, rgate + l * 768, 784, 768, 768, 2);
      // ---- self attention ----
      ln_kernel<<<784, 256, 0, stream>>>(local_f, ln1_w + l * 768, ln1_b + l * 768, ln_bf);
      G(T64, ln_bf, 768, w_qkv, 768, qkv_b + (size_t)l * 2304,
        nullptr, kv_bf, 2304, nullptr, nullptr, 784, 2304, 768, 0);
      attn_k<<<dim3(B_ * NH_, 2), 256, 0, stream>>>(kv_bf, 2304, 0, 49,
          kv_bf, 2304, 768, 1536, 49, l_cos, l_sin, N_ * 32, l_cos, l_sin, N_ * 32, act_bf);
      G(T64, act_bf, 768, w_ao, 768, ao_b + l * 768,
        local_f, local_bf, 768, local_f, nullptr, 784, 768, 768, 2);
      // ---- MLP ----
      ln_kernel<<<784, 256, 0, stream>>>(local_f, ln2_w + l * 768, ln2_b + l * 768, ln_bf);
      G(T64, ln_bf, 768, w_m1, 768, m1_b + (size_t)l * 3072,
        nullptr, act_bf, 3072, nullptr, nullptr, 784, 3072, 768, 1);
      G(T64, act_bf, 3072, w_m2, 3072, m2_b + l * 768,
        local_f, local_bf, 768, local_f, nullptr, 784, 768, 3072, 2);
      // ---- write cross: scene queries local KV ----
      G(T64, local_bf, 768, w_wkv, 768, wkv_b + (size_t)l * 1536,
        nullptr, kv_bf, 1536, nullptr, nullptr, 784, 1536, 768, 0);
      attn_k<<<dim3(B_ * NH_, 4), 256, 0, stream>>>(qrkv_bf, 2304, 0, 256,
          kv_bf, 1536, 0, 768, 49, sc_cos, sc_sin, 0, l_cos, l_sin, N_ * 32, act_bf);
      G(T128x64, act_bf, 768, w_wo, 768, wo_b + l * 768,
        scene_f, scene_bf, 768, scene_f, wgate + l * 768, 4096, 768, 768, 2);
    }
  }
}

// Round 6
// 6533.633 us; speedup vs baseline: 4.3599x; 1.3302x over previous
//
#include <hip/hip_runtime.h>

#define B_ 16
#define V_ 2
#define D_ 768
#define NH_ 12
#define L_ 12
#define DH_ 64
#define N_ 49
#define S_ 256

__device__ __forceinline__ unsigned short f2bf(float f) {
  unsigned int u = __builtin_bit_cast(unsigned int, f);
  u += 0x7fffu + ((u >> 16) & 1u);
  return (unsigned short)(u >> 16);
}
__device__ __forceinline__ float bf2f(unsigned short h) {
  unsigned int u = ((unsigned int)h) << 16;
  return __builtin_bit_cast(float, u);
}
__device__ __forceinline__ float bflo(unsigned int w) {
  return __builtin_bit_cast(float, w << 16);
}
__device__ __forceinline__ float bfhi(unsigned int w) {
  return __builtin_bit_cast(float, w & 0xffff0000u);
}
__device__ __forceinline__ unsigned int packbf2(float a, float b) {
  return (unsigned int)f2bf(a) | ((unsigned int)f2bf(b) << 16);
}

using bf16x8 = __attribute__((ext_vector_type(8))) __bf16;
using u16x8  = __attribute__((ext_vector_type(8))) unsigned short;
using f32x4  = __attribute__((ext_vector_type(4))) float;

__device__ __forceinline__ void g2l16(const unsigned short* g, unsigned short* l) {
  __builtin_amdgcn_global_load_lds(
      (const __attribute__((address_space(1))) unsigned int*)g,
      (__attribute__((address_space(3))) unsigned int*)l, 16, 0, 0);
}

// ---------------------------------------------------------------- GEMM ----
template <int BM, int BN, int BK>
__global__ __launch_bounds__(256) void gemm_v4(
    const unsigned short* __restrict__ A, int lda,
    const unsigned short* __restrict__ W, int ldw,
    const float* __restrict__ bias,
    float* __restrict__ Cf, unsigned short* __restrict__ Cb, int ldc,
    const float* __restrict__ res, const float* __restrict__ gate,
    int M, int N, int K, int epi)
{
  __shared__ unsigned short As[2][BM * BK];
  __shared__ unsigned short Bs[2][BN * BK];
  constexpr int FM = BM / 32, FN = BN / 32;
  constexpr int CPR = BK / 8;
  constexpr int LPS = (BM + BN) * BK / 2048;
  const int m0 = blockIdx.x * BM, n0 = blockIdx.y * BN;
  const int tid = threadIdx.x, lane = tid & 63, wid = tid >> 6;
  const int wr = wid >> 1, wc = wid & 1;
  const int fr = lane & 15, kq8 = lane >> 4;

  f32x4 acc[FM][FN];
#pragma unroll
  for (int mi = 0; mi < FM; ++mi)
#pragma unroll
    for (int ni = 0; ni < FN; ++ni) acc[mi][ni] = f32x4{0.f, 0.f, 0.f, 0.f};

  auto stage = [&](int buf, int k0) {
    const unsigned short* Ab = A + (size_t)m0 * lda + k0;
    const unsigned short* Bb = W + (size_t)n0 * ldw + k0;
#pragma unroll
    for (int ra = 0; ra < BM * BK / 2048; ++ra) {
      int c = ra * 256 + tid;
      int row = c / CPR, slot = c % CPR;
      int gslot = slot ^ (row & 7);
      g2l16(Ab + (size_t)row * lda + gslot * 8, &As[buf][c * 8]);
    }
#pragma unroll
    for (int rb = 0; rb < BN * BK / 2048; ++rb) {
      int c = rb * 256 + tid;
      int row = c / CPR, slot = c % CPR;
      int gslot = slot ^ (row & 7);
      g2l16(Bb + (size_t)row * ldw + gslot * 8, &Bs[buf][c * 8]);
    }
  };

  const int nt = K / BK;
  stage(0, 0);
  int cur = 0;
  for (int t = 0; t < nt; ++t) {
    if (t + 1 < nt) {
      stage(cur ^ 1, (t + 1) * BK);
      asm volatile("s_waitcnt vmcnt(%0)" :: "i"(LPS) : "memory");
    } else {
      asm volatile("s_waitcnt vmcnt(0)" ::: "memory");
    }
    __builtin_amdgcn_s_barrier();
#pragma unroll
    for (int ks = 0; ks < BK / 32; ++ks) {
      bf16x8 av[FM], bv[FN];
#pragma unroll
      for (int mi = 0; mi < FM; ++mi) {
        int row = wr * (BM / 2) + mi * 16 + fr;
        int idx = row * BK + (((ks * 4 + kq8) ^ (row & 7)) << 3);
        av[mi] = __builtin_bit_cast(bf16x8, *(const u16x8*)&As[cur][idx]);
      }
#pragma unroll
      for (int ni = 0; ni < FN; ++ni) {
        int row = wc * (BN / 2) + ni * 16 + fr;
        int idx = row * BK + (((ks * 4 + kq8) ^ (row & 7)) << 3);
        bv[ni] = __builtin_bit_cast(bf16x8, *(const u16x8*)&Bs[cur][idx]);
      }
#pragma unroll
      for (int mi = 0; mi < FM; ++mi)
#pragma unroll
        for (int ni = 0; ni < FN; ++ni)
          acc[mi][ni] = __builtin_amdgcn_mfma_f32_16x16x32_bf16(av[mi], bv[ni], acc[mi][ni], 0, 0, 0);
    }
    __builtin_amdgcn_s_barrier();
    cur ^= 1;
  }

  const int er = (lane >> 4) * 4, ec = lane & 15;
#pragma unroll
  for (int mi = 0; mi < FM; ++mi)
#pragma unroll
    for (int ni = 0; ni < FN; ++ni) {
      int gc = n0 + wc * (BN / 2) + ni * 16 + ec;
      float bi = bias ? bias[gc] : 0.0f;
      float gg = gate ? gate[gc] : 1.0f;
#pragma unroll
      for (int i = 0; i < 4; ++i) {
        int gr = m0 + wr * (BM / 2) + mi * 16 + er + i;
        if (gr < M) {
          float v = acc[mi][ni][i] + bi;
          if (epi == 1) {
            v = v / (1.0f + __expf(-1.59576912f * (v + 0.044715f * v * v * v)));
          } else if (epi == 2) {
            v = res[(size_t)gr * ldc + gc] + gg * v;
          }
          if (Cf) Cf[(size_t)gr * ldc + gc] = v;
          if (Cb) Cb[(size_t)gr * ldc + gc] = f2bf(v);
        }
      }
    }
}

// ------------------------------------------------------ MFMA attention ----
// Per (b,h) block, 4 waves; wave owns 16-row Q strip (qbase = y*64 + wid*16).
// S = Q.K^T via 16x16x32 MFMA (K bf16 chunk-swz); softmax in D-layout via
// 16-lane shfl reduce; P->LDS bf16 (per-wave, swz); PV with Vt (transposed,
// swz) as B-operand. 1/8 folded into K. Padded keys masked to -1e30.
template <int LKPAD>
__global__ __launch_bounds__(256) void attn_mfma(
    const unsigned short* __restrict__ Q, int ldq, int qoff, int Lq,
    const unsigned short* __restrict__ KV, int ldkv, int koff, int voff, int Lk,
    const float* __restrict__ cq, const float* __restrict__ sq, int rbq,
    const float* __restrict__ ck, const float* __restrict__ sk, int rbk,
    unsigned short* __restrict__ Out)
{
  constexpr int NT = LKPAD / 16;    // S column tiles
  constexpr int NKS = LKPAD / 32;   // PV k-steps
  __shared__ unsigned short Kb[LKPAD * 64];
  __shared__ unsigned short Vt[64 * LKPAD];
  __shared__ unsigned short Qs[4][16 * 64];
  __shared__ unsigned short Pl[4][16 * LKPAD];
  const int b = blockIdx.x / NH_, h = blockIdx.x - b * NH_;
  const int tid = threadIdx.x, lane = tid & 63, wid = tid >> 6;

  // ---- stage K (rope, scaled, row-swz) and V (transposed, swz) ----
  for (int idx = tid; idx < LKPAD * 32; idx += 256) {
    int t = idx >> 5, m = idx & 31;
    int d = 2 * m;
    int ksl = (t << 6) + (((m >> 2) ^ (t & 7)) << 3) + ((m & 3) << 1);
    int vs0 = d * LKPAD + (((t >> 3) ^ (d & 7)) << 3) + (t & 7);
    int vs1 = (d + 1) * LKPAD + (((t >> 3) ^ ((d + 1) & 7)) << 3) + (t & 7);
    if (t < Lk) {
      size_t rowb = ((size_t)b * Lk + t) * ldkv;
      unsigned int kw = *(const unsigned int*)(KV + rowb + koff + h * DH_ + d);
      unsigned int vw = *(const unsigned int*)(KV + rowb + voff + h * DH_ + d);
      float k1 = bflo(kw), k2 = bfhi(kw);
      size_t ri = (size_t)b * rbk + (size_t)t * 32 + m;
      float c = ck[ri], s = sk[ri];
      *(unsigned int*)&Kb[ksl] = packbf2((k1 * c - k2 * s) * 0.125f, (k1 * s + k2 * c) * 0.125f);
      Vt[vs0] = (unsigned short)(vw & 0xffff);
      Vt[vs1] = (unsigned short)(vw >> 16);
    } else {
      *(unsigned int*)&Kb[ksl] = 0;
      Vt[vs0] = 0; Vt[vs1] = 0;
    }
  }
  // ---- stage Q strip (per wave, rope, swz) ----
  const int qbase = blockIdx.y * 64 + wid * 16;
  for (int idx = lane; idx < 16 * 32; idx += 64) {
    int r = idx >> 5, m = idx & 31;
    int gq = qbase + r;
    unsigned int qr = 0;
    if (gq < Lq) {
      unsigned int qw = *(const unsigned int*)(Q + ((size_t)b * Lq + gq) * ldq + qoff + h * DH_ + 2 * m);
      float q1 = bflo(qw), q2 = bfhi(qw);
      size_t ri = (size_t)b * rbq + (size_t)gq * 32 + m;
      float c = cq[ri], s = sq[ri];
      qr = packbf2(q1 * c - q2 * s, q1 * s + q2 * c);
    }
    *(unsigned int*)&Qs[wid][(r << 6) + (((m >> 2) ^ (r & 7)) << 3) + ((m & 3) << 1)] = qr;
  }
  __syncthreads();

  const int fr = lane & 15, g = lane >> 4;
  bf16x8 qa[2];
#pragma unroll
  for (int ks = 0; ks < 2; ++ks)
    qa[ks] = __builtin_bit_cast(bf16x8,
        *(const u16x8*)&Qs[wid][(fr << 6) + ((((ks << 2) + g) ^ (fr & 7)) << 3)]);

  // ---- S = Q.K^T ----
  f32x4 sv[NT];
  __builtin_amdgcn_s_setprio(1);
#pragma unroll
  for (int t = 0; t < NT; ++t) {
    int key = (t << 4) + fr;
    f32x4 a = {0.f, 0.f, 0.f, 0.f};
#pragma unroll
    for (int ks = 0; ks < 2; ++ks) {
      bf16x8 kb = __builtin_bit_cast(bf16x8,
          *(const u16x8*)&Kb[(key << 6) + ((((ks << 2) + g) ^ (key & 7)) << 3)]);
      a = __builtin_amdgcn_mfma_f32_16x16x32_bf16(qa[ks], kb, a, 0, 0, 0);
    }
    sv[t] = a;
  }
  __builtin_amdgcn_s_setprio(0);
  // ---- mask padded keys ----
#pragma unroll
  for (int t = 0; t < NT; ++t) {
    int key = (t << 4) + fr;
    if (key >= Lk) sv[t] = f32x4{-1e30f, -1e30f, -1e30f, -1e30f};
  }
  // ---- softmax in D layout (row q = g*4+i, key = lane&15 + 16t) ----
  f32x4 mx = sv[0];
#pragma unroll
  for (int t = 1; t < NT; ++t)
#pragma unroll
    for (int i = 0; i < 4; ++i) mx[i] = fmaxf(mx[i], sv[t][i]);
#pragma unroll
  for (int off = 1; off <= 8; off <<= 1)
#pragma unroll
    for (int i = 0; i < 4; ++i) mx[i] = fmaxf(mx[i], __shfl_xor(mx[i], off));
  f32x4 sm = {0.f, 0.f, 0.f, 0.f};
#pragma unroll
  for (int t = 0; t < NT; ++t)
#pragma unroll
    for (int i = 0; i < 4; ++i) {
      float e = __expf(sv[t][i] - mx[i]);
      sv[t][i] = e;
      sm[i] += e;
    }
#pragma unroll
  for (int off = 1; off <= 8; off <<= 1)
#pragma unroll
    for (int i = 0; i < 4; ++i) sm[i] += __shfl_xor(sm[i], off);
  f32x4 inv;
#pragma unroll
  for (int i = 0; i < 4; ++i) inv[i] = 1.0f / sm[i];
  // ---- P -> LDS (bf16, per-wave, swz) ----
#pragma unroll
  for (int t = 0; t < NT; ++t) {
    int key = (t << 4) + fr;
    int chunk = key >> 3;
#pragma unroll
    for (int i = 0; i < 4; ++i) {
      int row = (g << 2) + i;
      Pl[wid][row * LKPAD + ((chunk ^ (row & 7)) << 3) + (key & 7)] = f2bf(sv[t][i]);
    }
  }
  // ---- O = P.V ----
  f32x4 oacc[4];
#pragma unroll
  for (int n = 0; n < 4; ++n) oacc[n] = f32x4{0.f, 0.f, 0.f, 0.f};
  __builtin_amdgcn_s_setprio(1);
#pragma unroll
  for (int ks = 0; ks < NKS; ++ks) {
    int chunk = (ks << 2) + g;
    bf16x8 pa = __builtin_bit_cast(bf16x8,
        *(const u16x8*)&Pl[wid][fr * LKPAD + ((chunk ^ (fr & 7)) << 3)]);
#pragma unroll
    for (int n = 0; n < 4; ++n) {
      int drow = (n << 4) + fr;
      bf16x8 vb = __builtin_bit_cast(bf16x8,
          *(const u16x8*)&Vt[drow * LKPAD + ((chunk ^ (drow & 7)) << 3)]);
      oacc[n] = __builtin_amdgcn_mfma_f32_16x16x32_bf16(pa, vb, oacc[n], 0, 0, 0);
    }
  }
  __builtin_amdgcn_s_setprio(0);
  // ---- store ----
#pragma unroll
  for (int n = 0; n < 4; ++n)
#pragma unroll
    for (int i = 0; i < 4; ++i) {
      int gq = qbase + (g << 2) + i;
      if (gq < Lq)
        Out[((size_t)b * Lq + gq) * D_ + h * DH_ + (n << 4) + fr] = f2bf(oacc[n][i] * inv[i]);
    }
}

// ----------------------------------------------------------- layernorm ----
__global__ __launch_bounds__(256) void ln_kernel(
    const float* __restrict__ X, const float* __restrict__ w,
    const float* __restrict__ bsh, unsigned short* __restrict__ Out)
{
  const int row = blockIdx.x, tid = threadIdx.x;
  const float* x = X + (size_t)row * D_;
  float v0 = x[tid], v1 = x[tid + 256], v2 = x[tid + 512];
  __shared__ float red[4];
  float s = v0 + v1 + v2;
  for (int o = 32; o; o >>= 1) s += __shfl_xor(s, o);
  if ((tid & 63) == 0) red[tid >> 6] = s;
  __syncthreads();
  float mean = (red[0] + red[1] + red[2] + red[3]) * (1.0f / 768.0f);
  float d0 = v0 - mean, d1 = v1 - mean, d2 = v2 - mean;
  float q = d0 * d0 + d1 * d1 + d2 * d2;
  __syncthreads();
  for (int o = 32; o; o >>= 1) q += __shfl_xor(q, o);
  if ((tid & 63) == 0) red[tid >> 6] = q;
  __syncthreads();
  float var = (red[0] + red[1] + red[2] + red[3]) * (1.0f / 768.0f);
  float rstd = rsqrtf(var + 1e-6f);
  Out[(size_t)row * D_ + tid]       = f2bf(d0 * rstd * w[tid]       + bsh[tid]);
  Out[(size_t)row * D_ + tid + 256] = f2bf(d1 * rstd * w[tid + 256] + bsh[tid + 256]);
  Out[(size_t)row * D_ + tid + 512] = f2bf(d2 * rstd * w[tid + 512] + bsh[tid + 512]);
}

// ------------------------------------------------------ weight convert ----
struct CvtA {
  const float* s[10];
  unsigned short* d[10];
  unsigned int lsrc[10];
  unsigned int lstride[10];
  int blkEnd[10];
};
__global__ __launch_bounds__(256) void cvt_multi_k(CvtA c) {
  int bid = blockIdx.x;
  int seg = 0;
#pragma unroll
  for (int i = 0; i < 9; ++i) seg += (bid >= c.blkEnd[i]) ? 1 : 0;
  unsigned int e = (unsigned int)(bid - (seg ? c.blkEnd[seg - 1] : 0)) * 2048u
                   + (unsigned int)threadIdx.x * 8u;
  unsigned int l = e / c.lsrc[seg], r = e - l * c.lsrc[seg];
  const float* s = c.s[seg] + e;
  unsigned short* d = c.d[seg] + (size_t)l * c.lstride[seg] + r;
  f32x4 a = *(const f32x4*)s, b2 = *(const f32x4*)(s + 4);
  u16x8 o;
  o[0] = f2bf(a.x); o[1] = f2bf(a.y); o[2] = f2bf(a.z); o[3] = f2bf(a.w);
  o[4] = f2bf(b2.x); o[5] = f2bf(b2.y); o[6] = f2bf(b2.z); o[7] = f2bf(b2.w);
  *(u16x8*)d = o;
}

__global__ void cvt_patch_k(const float* __restrict__ s, unsigned short* __restrict__ d) {
  int i = blockIdx.x * 256 + threadIdx.x;
  if (i >= 768 * 768) return;
  int r = i / 768, col = i - r * 768;
  d[i] = f2bf(col < 588 ? s[r * 588 + col] : 0.0f);
}

__global__ void fbias_k(const float* __restrict__ wqb, const float* __restrict__ rkvb,
                        float* __restrict__ fb) {
  int i = blockIdx.x * 256 + threadIdx.x;
  if (i >= L_ * 2304) return;
  int l = i / 2304, c = i - l * 2304;
  fb[i] = (c < 768) ? wqb[l * 768 + c] : rkvb[l * 1536 + (c - 768)];
}

// --------------------------------------------------------------- misc ----
__global__ void init_scene_k(const float* __restrict__ tok, float* __restrict__ sf,
                             unsigned short* __restrict__ sb, int total) {
  int i = blockIdx.x * 256 + threadIdx.x;
  if (i < total) {
    float v = tok[i % (S_ * D_)];
    sf[i] = v; sb[i] = f2bf(v);
  }
}

__global__ void rope_scene_k(float* __restrict__ c, float* __restrict__ s) {
  int idx = blockIdx.x * 256 + threadIdx.x;
  if (idx >= S_ * 32) return;
  int t = idx >> 5, m = idx & 31;
  int i = t >> 4, j = t & 15;
  float xx = -1.0f + 2.0f * j / 15.0f;
  float yy = -1.0f + 2.0f * i / 15.0f;
  float coord = (m < 16) ? xx : yy;
  float per = powf(100.0f, (float)(m & 15) / 16.0f);
  float ang = coord / per;
  c[idx] = cosf(ang); s[idx] = sinf(ang);
}

__global__ void rope_local_k(float* __restrict__ c, float* __restrict__ s,
                             const float* __restrict__ ctr, const float* __restrict__ scl) {
  int idx = blockIdx.x * 256 + threadIdx.x;
  if (idx >= B_ * N_ * 32) return;
  int b = idx / (N_ * 32);
  int r = idx - b * (N_ * 32);
  int pch = r >> 5, m = r & 31;
  int py = pch / 7, px = pch - py * 7;
  float cx = ctr[b * 2], cy = ctr[b * 2 + 1], sc = scl[b];
  float gx = cx + sc * ((px - 3.0f) / 3.0f);
  float gy = cy + sc * ((py - 3.0f) / 3.0f);
  float coord = (m < 16) ? gx : gy;
  float per = powf(100.0f, (float)(m & 15) / 16.0f);
  float ang = coord / per;
  c[idx] = cosf(ang); s[idx] = sinf(ang);
}

__global__ void im2col_k(unsigned short* __restrict__ xb, const float* __restrict__ img,
                         const float* __restrict__ ctr, const float* __restrict__ scl) {
  int idx = blockIdx.x * 256 + threadIdx.x;
  if (idx >= 784 * 768) return;
  int row = idx / 768, col = idx - row * 768;
  float val = 0.0f;
  if (col < 588) {
    int b = row / 49, pch = row - b * 49;
    int c = col / 196, rr = col - c * 196;
    int i = rr / 14, j = rr - i * 14;
    int py = pch / 7, px = pch - py * 7;
    int gyi = py * 14 + i, gxi = px * 14 + j;
    float cx = ctr[b * 2], cy = ctr[b * 2 + 1], sc = scl[b];
    float gy = cy + sc * (-1.0f + 2.0f * gyi / 97.0f);
    float gx = cx + sc * (-1.0f + 2.0f * gxi / 97.0f);
    float pyi = (gy + 1.0f) * 0.5f * 223.0f;
    float pxi = (gx + 1.0f) * 0.5f * 223.0f;
    float y0f = fminf(fmaxf(floorf(pyi), 0.0f), 222.0f);
    float x0f = fminf(fmaxf(floorf(pxi), 0.0f), 222.0f);
    int y0 = (int)y0f, x0 = (int)x0f;
    float wy = fminf(fmaxf(pyi - y0f, 0.0f), 1.0f);
    float wx = fminf(fmaxf(pxi - x0f, 0.0f), 1.0f);
    const float* base = img + (size_t)(b * 3 + c) * 224 * 224;
    float v00 = base[y0 * 224 + x0],       v01 = base[y0 * 224 + x0 + 1];
    float v10 = base[(y0 + 1) * 224 + x0], v11 = base[(y0 + 1) * 224 + x0 + 1];
    val = (v00 * (1.0f - wy) + v10 * wy) * (1.0f - wx) + (v01 * (1.0f - wy) + v11 * wy) * wx;
  }
  xb[idx] = f2bf(val);
}

// -------------------------------------------------------------- launch ----
extern "C" void kernel_launch(void* const* d_in, const int* in_sizes, int n_in,
                              void* d_out, int out_size, void* d_ws, size_t ws_size,
                              hipStream_t stream) {
  const float* images    = (const float*)d_in[0];
  const float* centers   = (const float*)d_in[1];
  const float* scales    = (const float*)d_in[2];
  const float* patch_w   = (const float*)d_in[3];
  const float* patch_b   = (const float*)d_in[4];
  const float* scene_tok = (const float*)d_in[5];
  const float* ln1_w = (const float*)d_in[6];
  const float* ln1_b = (const float*)d_in[7];
  const float* ln2_w = (const float*)d_in[8];
  const float* ln2_b = (const float*)d_in[9];
  const float* qkv_w = (const float*)d_in[10];
  const float* qkv_b = (const float*)d_in[11];
  const float* ao_w  = (const float*)d_in[12];
  const float* ao_b  = (const float*)d_in[13];
  const float* m1_w  = (const float*)d_in[14];
  const float* m1_b  = (const float*)d_in[15];
  const float* m2_w  = (const float*)d_in[16];
  const float* m2_b  = (const float*)d_in[17];
  const float* rq_w  = (const float*)d_in[18];
  const float* rq_b  = (const float*)d_in[19];
  const float* rkv_w = (const float*)d_in[20];
  const float* rkv_b = (const float*)d_in[21];
  const float* ro_w  = (const float*)d_in[22];
  const float* ro_b  = (const float*)d_in[23];
  const float* rgate = (const float*)d_in[24];
  const float* wq_w  = (const float*)d_in[25];
  const float* wq_b  = (const float*)d_in[26];
  const float* wkv_w = (const float*)d_in[27];
  const float* wkv_b = (const float*)d_in[28];
  const float* wo_w  = (const float*)d_in[29];
  const float* wo_b  = (const float*)d_in[30];
  const float* wgate = (const float*)d_in[31];

  float* scene_f = (float*)d_out;

  char* p = (char*)d_ws;
  auto alloc = [&](size_t bytes) { char* r = p; p += (bytes + 255) & ~(size_t)255; return (void*)r; };
  unsigned short* scene_bf = (unsigned short*)alloc((size_t)4096 * 768 * 2);
  float*          local_f  = (float*)alloc((size_t)784 * 768 * 4);
  unsigned short* local_bf = (unsigned short*)alloc((size_t)832 * 768 * 2);
  unsigned short* q_r_bf   = (unsigned short*)alloc((size_t)784 * 768 * 2);
  unsigned short* qrkv_bf  = (unsigned short*)alloc((size_t)4096 * 2304 * 2);
  unsigned short* kv_bf    = (unsigned short*)alloc((size_t)784 * 2304 * 2);
  unsigned short* ln_bf    = (unsigned short*)alloc((size_t)832 * 768 * 2);
  unsigned short* act_bf   = (unsigned short*)alloc((size_t)4096 * 768 * 2);
  unsigned short* x_bf     = (unsigned short*)alloc((size_t)832 * 768 * 2);
  float* sc_cos = (float*)alloc((size_t)S_ * 32 * 4);
  float* sc_sin = (float*)alloc((size_t)S_ * 32 * 4);
  float* l_cos  = (float*)alloc((size_t)B_ * N_ * 32 * 4);
  float* l_sin  = (float*)alloc((size_t)B_ * N_ * 32 * 4);
  unsigned short* patch_wbf = (unsigned short*)alloc((size_t)768 * 768 * 2);
  float*          fb        = (float*)alloc((size_t)L_ * 2304 * 4);

  static const unsigned int LSRC[10] = {589824, 589824, 1179648, 589824, 1769472,
                                        589824, 2359296, 2359296, 1179648, 589824};
  static const unsigned int LSTR[10] = {589824, 1769472, 1769472, 589824, 1769472,
                                        589824, 2359296, 2359296, 1179648, 589824};
  static const unsigned int DOFF[10] = {0, 0, 589824, 0, 0, 0, 0, 0, 0, 0};
  const float* WSRC[10] = {rq_w, wq_w, rkv_w, ro_w, qkv_w, ao_w, m1_w, m2_w, wkv_w, wo_w};
  static const size_t REGSZ[9] = {589824, 1769472, 589824, 1769472, 589824,
                                  2359296, 2359296, 1179648, 589824};
  size_t regBase[9];
  size_t allElemsPerLayer = 0;
  {
    size_t cur = 0;
    for (int i = 0; i < 9; ++i) { regBase[i] = cur; cur += REGSZ[i] * L_; allElemsPerLayer += REGSZ[i]; }
  }
  const size_t allElems = allElemsPerLayer * L_;
  size_t usedBytes = (size_t)(p - (char*)d_ws);
  bool preconv = ws_size >= usedBytes + allElems * 2 + 4096;
  unsigned short* wbf = (unsigned short*)alloc((preconv ? allElems : allElemsPerLayer) * 2);

  enum { T128, T128x64, T64 };
  auto G = [&](int tile, const unsigned short* A, int lda, const unsigned short* Wp, int ldw,
               const float* bias, float* Cf, unsigned short* Cb, int ldc,
               const float* res, const float* gt, int M, int N, int K, int epi) {
    if (tile == T128)
      gemm_v4<128, 128, 64><<<dim3(M / 128, N / 128), 256, 0, stream>>>(
          A, lda, Wp, ldw, bias, Cf, Cb, ldc, res, gt, M, N, K, epi);
    else if (tile == T128x64)
      gemm_v4<128, 64, 64><<<dim3(M / 128, N / 64), 256, 0, stream>>>(
          A, lda, Wp, ldw, bias, Cf, Cb, ldc, res, gt, M, N, K, epi);
    else
      gemm_v4<64, 64, 128><<<dim3((M + 63) / 64, N / 64), 256, 0, stream>>>(
          A, lda, Wp, ldw, bias, Cf, Cb, ldc, res, gt, M, N, K, epi);
  };

  {
    int total = B_ * S_ * D_;
    init_scene_k<<<(total + 255) / 256, 256, 0, stream>>>(scene_tok, scene_f, scene_bf, total);
    rope_scene_k<<<(S_ * 32 + 255) / 256, 256, 0, stream>>>(sc_cos, sc_sin);
    cvt_patch_k<<<(768 * 768 + 255) / 256, 256, 0, stream>>>(patch_w, patch_wbf);
    fbias_k<<<(L_ * 2304 + 255) / 256, 256, 0, stream>>>(wq_b, rkv_b, fb);
    if (preconv) {
      CvtA cv;
      int blk = 0;
      for (int i = 0; i < 10; ++i) {
        int reg = i >= 2 ? i - 1 : i;
        cv.s[i] = WSRC[i];
        cv.d[i] = wbf + regBase[reg] + DOFF[i];
        cv.lsrc[i] = LSRC[i];
        cv.lstride[i] = LSTR[i];
        blk += (int)((size_t)LSRC[i] * L_ / 2048);
        cv.blkEnd[i] = blk;
      }
      cvt_multi_k<<<blk, 256, 0, stream>>>(cv);
    }
  }

  for (int vp = 0; vp < V_; ++vp) {
    const float* ctr = centers + (size_t)vp * B_ * 2;
    const float* scl = scales + (size_t)vp * B_;
    rope_local_k<<<(B_ * N_ * 32 + 255) / 256, 256, 0, stream>>>(l_cos, l_sin, ctr, scl);
    im2col_k<<<(784 * 768 + 255) / 256, 256, 0, stream>>>(x_bf, images, ctr, scl);
    G(T64, x_bf, 768, patch_wbf, 768, patch_b, local_f, local_bf, 768,
      nullptr, nullptr, 784, 768, 768, 0);

    for (int l = 0; l < L_; ++l) {
      const unsigned short* wL[10];
      if (preconv) {
        for (int i = 0; i < 10; ++i) {
          int reg = i >= 2 ? i - 1 : i;
          wL[i] = wbf + regBase[reg] + (size_t)l * LSTR[i] + DOFF[i];
        }
      } else {
        CvtA cv;
        int blk = 0;
        size_t cur = 0;
        size_t rb[9];
        for (int i = 0; i < 10; ++i) {
          int reg = i >= 2 ? i - 1 : i;
          if (i != 2) { rb[reg] = cur; cur += REGSZ[reg]; }
          cv.s[i] = WSRC[i] + (size_t)l * LSRC[i];
          cv.d[i] = wbf + rb[reg] + DOFF[i];
          cv.lsrc[i] = LSRC[i];
          cv.lstride[i] = LSTR[i];
          blk += (int)(LSRC[i] / 2048);
          cv.blkEnd[i] = blk;
          wL[i] = (unsigned short*)cv.d[i];
        }
        cvt_multi_k<<<blk, 256, 0, stream>>>(cv);
      }
      const unsigned short *w_rq = wL[0], *w_qrkv = wL[1], *w_ro = wL[3], *w_qkv = wL[4],
                           *w_ao = wL[5], *w_m1 = wL[6], *w_m2 = wL[7], *w_wkv = wL[8],
                           *w_wo = wL[9];

      // ---- fused wq+rkv on scene; rq on local ----
      G(T128, scene_bf, 768, w_qrkv, 768, fb + (size_t)l * 2304,
        nullptr, qrkv_bf, 2304, nullptr, nullptr, 4096, 2304, 768, 0);
      G(T64, local_bf, 768, w_rq, 768, rq_b + l * 768,
        nullptr, q_r_bf, 768, nullptr, nullptr, 784, 768, 768, 0);
      // ---- read cross: local queries scene KV ----
      attn_mfma<256><<<dim3(B_ * NH_, 1), 256, 0, stream>>>(q_r_bf, 768, 0, 49,
          qrkv_bf, 2304, 768, 1536, 256, l_cos, l_sin, N_ * 32, sc_cos, sc_sin, 0, act_bf);
      G(T64, act_bf, 768, w_ro, 768, ro_b + l * 768,
        local_f, local_bf, 768, local_f, rgate + l * 768, 784, 768, 768, 2);
      // ---- self attention ----
      ln_kernel<<<784, 256, 0, stream>>>(local_f, ln1_w + l * 768, ln1_b + l * 768, ln_bf);
      G(T64, ln_bf, 768, w_qkv, 768, qkv_b + (size_t)l * 2304,
        nullptr, kv_bf, 2304, nullptr, nullptr, 784, 2304, 768, 0);
      attn_mfma<64><<<dim3(B_ * NH_, 1), 256, 0, stream>>>(kv_bf, 2304, 0, 49,
          kv_bf, 2304, 768, 1536, 49, l_cos, l_sin, N_ * 32, l_cos, l_sin, N_ * 32, act_bf);
      G(T64, act_bf, 768, w_ao, 768, ao_b + l * 768,
        local_f, local_bf, 768, local_f, nullptr, 784, 768, 768, 2);
      // ---- MLP ----
      ln_kernel<<<784, 256, 0, stream>>>(local_f, ln2_w + l * 768, ln2_b + l * 768, ln_bf);
      G(T64, ln_bf, 768, w_m1, 768, m1_b + (size_t)l * 3072,
        nullptr, act_bf, 3072, nullptr, nullptr, 784, 3072, 768, 1);
      G(T64, act_bf, 3072, w_m2, 3072, m2_b + l * 768,
        local_f, local_bf, 768, local_f, nullptr, 784, 768, 3072, 2);
      // ---- write cross: scene queries local KV ----
      G(T64, local_bf, 768, w_wkv, 768, wkv_b + (size_t)l * 1536,
        nullptr, kv_bf, 1536, nullptr, nullptr, 784, 1536, 768, 0);
      attn_mfma<64><<<dim3(B_ * NH_, 4), 256, 0, stream>>>(qrkv_bf, 2304, 0, 256,
          kv_bf, 1536, 0, 768, 49, sc_cos, sc_sin, 0, l_cos, l_sin, N_ * 32, act_bf);
      G(T128x64, act_bf, 768, w_wo, 768, wo_b + l * 768,
        scene_f, scene_bf, 768, scene_f, wgate + l * 768, 4096, 768, 768, 2);
    }
  }
}